// Round 7
// baseline (447.768 us; speedup 1.0000x reference)
//
#include <hip/hip_runtime.h>
#include <math.h>

#define KK 8
#define H 250          // SIZE == h1
#define MDIM 576
#define NB 2048
#define HA 100
#define ROWS (NB*KK)   // 16384
#define PROWS (ROWS*7) // 114688 pair rows
#define PQS 512        // PQb row stride (ushort): P at 0..249, Q at 256..505
#define KP 1088        // padded K for out GEMM (1076 -> 34*32)
#define NGB 9          // groups per k_cseff block (63 pair rows)
#define EPS 1e-5f

typedef unsigned short ushort_t;
typedef short short8 __attribute__((ext_vector_type(8)));
typedef unsigned short us8 __attribute__((ext_vector_type(8)));
typedef unsigned short us4 __attribute__((ext_vector_type(4)));
typedef unsigned short us2 __attribute__((ext_vector_type(2)));
typedef float f32x4 __attribute__((ext_vector_type(4)));

// ---- DPP helpers (old=0 + bound_ctrl=1 so GCNDPPCombine folds to v_add_f32_dpp) ----
template<int CTRL>
__device__ __forceinline__ float dpp_add_f32(float x) {
    const int s = __builtin_amdgcn_update_dpp(
        0, __builtin_bit_cast(int, x), CTRL, 0xF, 0xF, true);
    return x + __builtin_bit_cast(float, s);
}
// full-wave (64-lane) sum; result broadcast wave-uniform via readlane(63)
__device__ __forceinline__ float wave_sum_dpp(float x) {
    x = dpp_add_f32<0x111>(x);  // row_shr:1
    x = dpp_add_f32<0x112>(x);  // row_shr:2
    x = dpp_add_f32<0x114>(x);  // row_shr:4
    x = dpp_add_f32<0x118>(x);  // row_shr:8
    x = dpp_add_f32<0x142>(x);  // row_bcast:15
    x = dpp_add_f32<0x143>(x);  // row_bcast:31 -> lane 63 holds total
    return __builtin_bit_cast(float, __builtin_amdgcn_readlane(
        __builtin_bit_cast(int, x), 63));
}
// 16-lane butterfly sum: result present in ALL 16 lanes of each 16-lane row
__device__ __forceinline__ float bfly16_sum(float x) {
    x = dpp_add_f32<0xB1>(x);   // quad_perm [1,0,3,2]  (xor 1)
    x = dpp_add_f32<0x4E>(x);   // quad_perm [2,3,0,1]  (xor 2)
    x = dpp_add_f32<0x141>(x);  // row_half_mirror      (pairs across quads)
    x = dpp_add_f32<0x140>(x);  // row_mirror           (pairs across halves)
    return x;
}

__device__ __forceinline__ void async_copy16(const void* g, void* l) {
    __builtin_amdgcn_global_load_lds(
        (const __attribute__((address_space(1))) void*)g,
        (__attribute__((address_space(3))) void*)l, 16, 0, 0);
}

__device__ __forceinline__ ushort_t f2bf(float v) {
    union { float f; unsigned int u; } c; c.f = v;
    unsigned int x = c.u;
    x += 0x7fff + ((x >> 16) & 1);   // RNE
    return (ushort_t)(x >> 16);
}
__device__ __forceinline__ float bf2f(ushort_t v) {
    union { unsigned int u; float f; } c; c.u = ((unsigned int)v) << 16;
    return c.f;
}
// fast tanh: 1 - 2/(exp(2x)+1)  (v_exp + v_rcp; ~1e-6 rel err, << bf16 ulp)
__device__ __forceinline__ float ftanh(float x) {
    const float e = __expf(2.f * x);
    return 1.f - 2.f * __builtin_amdgcn_rcpf(e + 1.f);
}
__device__ __forceinline__ float fsigmoid(float x) {
    return __builtin_amdgcn_rcpf(1.f + __expf(-x));
}

// ---- fused prep: Wt | Wpq | Wca | Wenc | Sb | x->Abuf ----
__global__ __launch_bounds__(256) void k_prep(
    const float* __restrict__ out_W, const float* __restrict__ core_W,
    const float* __restrict__ ctx_W, const float* __restrict__ att_W1,
    const float* __restrict__ enc_W, const float* __restrict__ state,
    const float* __restrict__ x,
    ushort_t* __restrict__ Wt, ushort_t* __restrict__ Wpq,
    ushort_t* __restrict__ Wca, ushort_t* __restrict__ Wenc,
    ushort_t* __restrict__ Sb, ushort_t* __restrict__ Abuf)
{
    const int b = blockIdx.x, t = threadIdx.x;
    if (b < 256) {                      // Wt[n][k] = out_W[k][n]
        const int n = b;
        for (int k = t; k < KP; k += 256) {
            const float v = (n < H && k < 1076) ? out_W[(size_t)k * H + n] : 0.f;
            Wt[(size_t)n * KP + k] = f2bf(v);
        }
    } else if (b < 768) {               // Wpq
        const int n = b - 256, k = t;
        float v = 0.f;
        if (k < H) {
            if (n < H)                    v = core_W[(size_t)k * H + n];
            else if (n >= 256 && n < 506) v = core_W[(size_t)(H + k) * H + (n - 256)];
        }
        Wpq[(size_t)n * 256 + k] = f2bf(v);
    } else if (b < 1152) {              // Wca
        const int n = b - 768, k = t;
        float v = 0.f;
        if (k < H) {
            if (n < H)           v = ctx_W[(size_t)k * H + n];
            else if (n < H + HA) v = att_W1[(size_t)k * HA + (n - H)];
        }
        Wca[(size_t)n * 256 + k] = f2bf(v);
    } else if (b < 1408) {              // Wenc[n][k] = enc_W[k][n]
        const int n = b - 1152, k = t;
        const float v = (n < H && k < H) ? enc_W[(size_t)k * H + n] : 0.f;
        Wenc[(size_t)n * 256 + k] = f2bf(v);
    } else if (b < 2432) {              // Sb: state padded to 256, bf16
        const int r0 = (b - 1408) * 16;
        for (int idx = t; idx < 16 * 256; idx += 256) {
            const int r = r0 + (idx >> 8), k = idx & 255;
            const float v = (k < H) ? state[(size_t)r * H + k] : 0.f;
            Sb[(size_t)r * 256 + k] = f2bf(v);
        }
    } else {                            // Abuf cols [500,1088): x + pad
        const int row = b - 2432;
        for (int c = 500 + t; c < KP; c += 256) {
            const float v = (c < 500 + MDIM) ? x[(size_t)row * MDIM + (c - 500)] : 0.f;
            Abuf[(size_t)row * KP + c] = f2bf(v);
        }
    }
}

// N-resident bf16 MFMA GEMM (k_cs-style): C[m][n] = sum_k A[m][k]*B[n][k] (+bias)
// Whole N = NT*64 resident in LDS per block -> A fetched exactly once.
// 512 thr = 8 waves (2m x 4n); per wave 32 rows x NT*16 cols; acc[2][NT].
template<int NT>
__global__ __launch_bounds__(512, NT == 8 ? 2 : 4) void k_gemm_nres(
    const ushort_t* __restrict__ A, int lda,
    const ushort_t* __restrict__ B, int ldb,
    void* __restrict__ Cp, int ldc,
    const float* __restrict__ bias,
    int ksteps, int nlim, int bf16out)
{
    constexpr int NROWS = NT * 64;                    // B rows resident
    __shared__ __align__(16) ushort_t As[64 * 32];    // 4 KB
    __shared__ __align__(16) ushort_t Bs[NROWS * 32]; // NT*4 KB
    const int tid = threadIdx.x, lane = tid & 63, wave = tid >> 6;
    const int wm = wave >> 2, wn = wave & 3;
    const int R0 = (int)blockIdx.x * 64;

    const int ar = tid >> 2, acb = tid & 3;
    const bool aon = tid < 256;
    const int acl = acb ^ ((ar >> 1) & 3);
    const ushort_t* gA = A + (size_t)(R0 + ar) * lda + acl * 8;

    const int q = lane >> 4, fr = lane & 15;

    f32x4 acc[2][NT] = {};
    for (int ks = 0; ks < ksteps; ++ks) {
        const int k0 = ks * 32;
        if (aon) async_copy16(gA + k0, &As[tid * 8]);
#pragma unroll
        for (int it = 0; it < NT / 2; ++it) {
            const int ci  = it * 512 + tid;
            const int rb  = ci >> 2, cb2 = ci & 3;
            const int clb = cb2 ^ ((rb >> 1) & 3);
            async_copy16(B + (size_t)rb * ldb + k0 + clb * 8, &Bs[ci * 8]);
        }
        __syncthreads();
        short8 a[2];
#pragma unroll
        for (int ms = 0; ms < 2; ++ms) {
            const int row = wm * 32 + ms * 16 + fr;
            a[ms] = *(const short8*)&As[(row * 4 + (q ^ ((row >> 1) & 3))) * 8];
        }
#pragma unroll
        for (int nt = 0; nt < NT; ++nt) {
            const int n = wn * (NT * 16) + nt * 16 + fr;
            const short8 b = *(const short8*)&Bs[(n * 4 + (q ^ ((n >> 1) & 3))) * 8];
#pragma unroll
            for (int ms = 0; ms < 2; ++ms)
                acc[ms][nt] = __builtin_amdgcn_mfma_f32_16x16x32_bf16(
                    a[ms], b, acc[ms][nt], 0, 0, 0);
        }
        __syncthreads();
    }

#pragma unroll
    for (int ms = 0; ms < 2; ++ms)
#pragma unroll
        for (int nt = 0; nt < NT; ++nt) {
            const int col = wn * (NT * 16) + nt * 16 + fr;
            if (col >= nlim) continue;
            const float bv = bias ? bias[col] : 0.f;
#pragma unroll
            for (int reg = 0; reg < 4; ++reg) {
                const int row = R0 + wm * 32 + ms * 16 + q * 4 + reg;
                const float v = acc[ms][nt][reg] + bv;
                if (bf16out) ((ushort_t*)Cp)[(size_t)row * ldc + col] = f2bf(v);
                else         ((float*)Cp)[(size_t)row * ldc + col] = v;
            }
        }
}

// LN(relu(Epre + enc_b)) -> Abuf cols [0,250). One wave per row, us4 loads.
__global__ __launch_bounds__(256) void k_lnenc(const ushort_t* __restrict__ Epre,
    const float* __restrict__ eb, const float* __restrict__ eg,
    const float* __restrict__ ebt, ushort_t* __restrict__ Abuf)
{
    const int wave = threadIdx.x >> 6, lane = threadIdx.x & 63;
    const int row = blockIdx.x * 4 + wave;
    const int c0 = 4 * lane;

    const us4 v = *(const us4*)&Epre[(size_t)row * 256 + c0];
    float y[4]; float sm = 0.f, sq = 0.f;
#pragma unroll
    for (int t = 0; t < 4; ++t) {
        const int cc = c0 + t;
        float z = 0.f;
        if (cc < H) z = fmaxf(bf2f(v[t]) + eb[cc], 0.f);
        y[t] = z; sm += z; sq += z * z;
    }
    sm = wave_sum_dpp(sm);
    sq = wave_sum_dpp(sq);
    const float mu = sm * (1.f / H);
    const float rs = __builtin_amdgcn_rsqf(sq * (1.f / H) - mu * mu + EPS);
    ushort_t o[4];
#pragma unroll
    for (int t = 0; t < 4; ++t) {
        const int cc = c0 + t;
        o[t] = (cc < H) ? f2bf((y[t] - mu) * rs * eg[cc] + ebt[cc]) : (ushort_t)0;
    }
    ushort_t* dst = Abuf + (size_t)row * KP + c0;
    if (c0 + 3 < H) { *(us4*)dst = (us4){o[0], o[1], o[2], o[3]}; }
    else {
        if (c0 + 1 < H) *(us2*)dst = (us2){o[0], o[1]};
    }
}

// Co[r][0:256] = LN(relu(P_g + Q_qr + core_b)) bf16. One wave per GROUP.
// All 7 partner Q rows prefetched; per-row sums reduced via DPP trees.
__global__ __launch_bounds__(256) void k_core(const ushort_t* __restrict__ PQb,
    const float* __restrict__ core_b, const float* __restrict__ core_g,
    const float* __restrict__ core_bt, ushort_t* __restrict__ Co)
{
    const int wave = threadIdx.x >> 6, lane = threadIdx.x & 63;
    const int g = blockIdx.x * 4 + wave;        // group 0..16383
    const int i = g & 7;
    const int c = lane * 4;

    const us4 pu = *(const us4*)&PQb[(size_t)g * PQS + c];
    us4 qu[7];
#pragma unroll
    for (int jj = 0; jj < 7; ++jj) {
        const int j = jj + (jj >= i ? 1 : 0);
        const int qr = (g & ~7) + j;
        qu[jj] = *(const us4*)&PQb[(size_t)qr * PQS + 256 + c];
    }
    float pe[4], cb[4], cg[4], cbt[4]; bool vl[4];
#pragma unroll
    for (int t = 0; t < 4; ++t) {
        vl[t]  = (c + t) < H;
        pe[t]  = bf2f(pu[t]);
        cb[t]  = vl[t] ? core_b[c + t]  : 0.f;
        cg[t]  = vl[t] ? core_g[c + t]  : 0.f;
        cbt[t] = vl[t] ? core_bt[c + t] : 0.f;
    }
    float z[7][4], red[7][2];
#pragma unroll
    for (int jj = 0; jj < 7; ++jj) {
        float sm = 0.f, sq = 0.f;
#pragma unroll
        for (int t = 0; t < 4; ++t) {
            const float zz = vl[t] ? fmaxf(pe[t] + bf2f(qu[jj][t]) + cb[t], 0.f) : 0.f;
            z[jj][t] = zz; sm += zz; sq = fmaf(zz, zz, sq);
        }
        red[jj][0] = sm; red[jj][1] = sq;
    }
    // 14 independent DPP reduction chains (VALU only, no DS pipe)
#pragma unroll
    for (int jj = 0; jj < 7; ++jj) {
        red[jj][0] = wave_sum_dpp(red[jj][0]);
        red[jj][1] = wave_sum_dpp(red[jj][1]);
    }
#pragma unroll
    for (int jj = 0; jj < 7; ++jj) {
        const float mu = red[jj][0] * (1.f / H);
        const float rs = __builtin_amdgcn_rsqf(red[jj][1] * (1.f / H) - mu * mu + EPS);
        us4 o;
#pragma unroll
        for (int t = 0; t < 4; ++t)
            o[t] = vl[t] ? f2bf((z[jj][t] - mu) * rs * cg[t] + cbt[t]) : (ushort_t)0;
        *(us4*)&Co[((size_t)g * 7 + jj) * 256 + c] = o;
    }
}

// ================= k_cseff: k_cs GEMM + eff epilogue =================
// Block = 9 groups (63 pair rows; M=64 tile, row 63 = clamped dup, discarded).
// GEMM: verbatim k_cs (Co staged via global_load_lds, Wca N=384 per-ks).
// Epilogue: relu/tanh transform + bfly16 + red LDS + wave0 gates +
// ds_add_f32 accumulation into per-group effacc + eff write (no Cs buffer).
__global__ __launch_bounds__(512, 4) void k_cseff(
    const ushort_t* __restrict__ Co,
    const ushort_t* __restrict__ Wca,   // [384][256] bf16
    const float* __restrict__ ctx_b, const float* __restrict__ ctx_g,
    const float* __restrict__ ctx_bt,
    const float* __restrict__ att_b1, const float* __restrict__ att_g,
    const float* __restrict__ att_bt,
    const float* __restrict__ attW2, const float* __restrict__ att_b2,
    ushort_t* __restrict__ Abuf)
{
    __shared__ __align__(16) ushort_t As[64 * 32];    // 4 KB
    __shared__ __align__(16) ushort_t Bs[384 * 32];   // 24 KB
    __shared__ __align__(16) float red[64][36];       // 9.2 KB
    __shared__ __align__(16) float scal[64][4];       // cj, ag, cj*muC
    __shared__ __align__(16) float effacc[NGB * 252]; // 9.1 KB
    __shared__ float sS0[NGB], sS1[NGB];
    __shared__ float swred[4][2];

    const int tid = threadIdx.x, lane = tid & 63, wave = tid >> 6;
    const int wm = wave >> 2, wn = wave & 3;
    const int q = lane >> 4, fr = lane & 15;
    const int gb0 = (int)blockIdx.x * NGB;
    const int ngroups = min(NGB, ROWS - gb0);
    const int nrows = ngroups * 7;
    const int R0r = gb0 * 7;

    // zero cross-phase accumulators (visible after first ks barrier)
    for (int i = tid; i < NGB * 252; i += 512) effacc[i] = 0.f;

    // ---- GEMM phase (k_cs verbatim; A row clamped to valid range) ----
    const int ar = tid >> 2, acb = tid & 3;
    const bool aon = tid < 256;
    const int acl = acb ^ ((ar >> 1) & 3);
    const int arr = (ar < nrows) ? ar : (nrows - 1);
    const ushort_t* gA = Co + (size_t)(R0r + arr) * 256 + acl * 8;

    f32x4 acc[2][6] = {};
    for (int ks = 0; ks < 8; ++ks) {
        const int k0 = ks * 32;
        if (aon) async_copy16(gA + k0, &As[tid * 8]);
#pragma unroll
        for (int it = 0; it < 3; ++it) {
            const int ci  = it * 512 + tid;
            const int rb  = ci >> 2, cb2 = ci & 3;
            const int clb = cb2 ^ ((rb >> 1) & 3);
            async_copy16(Wca + (size_t)rb * 256 + k0 + clb * 8, &Bs[ci * 8]);
        }
        __syncthreads();
        short8 a[2];
#pragma unroll
        for (int ms = 0; ms < 2; ++ms) {
            const int row = wm * 32 + ms * 16 + fr;
            a[ms] = *(const short8*)&As[(row * 4 + (q ^ ((row >> 1) & 3))) * 8];
        }
#pragma unroll
        for (int nt = 0; nt < 6; ++nt) {
            const int n = wn * 96 + nt * 16 + fr;
            const short8 b = *(const short8*)&Bs[(n * 4 + (q ^ ((n >> 1) & 3))) * 8];
#pragma unroll
            for (int ms = 0; ms < 2; ++ms)
                acc[ms][nt] = __builtin_amdgcn_mfma_f32_16x16x32_bf16(
                    a[ms], b, acc[ms][nt], 0, 0, 0);
        }
        __syncthreads();
    }

    // ---- epilogue: per-col constants loaded NOW (keeps GEMM regs = k_cs) ----
    bool eC[6], eA[6];
    float b_[6], gw[6];
    float psgw = 0.f, psbw = 0.f;
#pragma unroll
    for (int nt = 0; nt < 6; ++nt) {
        const int col = wn * 96 + nt * 16 + fr;
        eC[nt] = col < H;
        eA[nt] = (col >= H) && (col < H + HA);
        if (eC[nt]) { b_[nt] = ctx_b[col]; gw[nt] = 0.f; }
        else if (eA[nt]) {
            const int ca = col - H;
            b_[nt] = att_b1[ca];
            const float w2 = attW2[ca];
            gw[nt] = att_g[ca] * w2;
            psgw += gw[nt]; psbw += att_bt[ca] * w2;
        } else { b_[nt] = gw[nt] = 0.f; }
    }
    psgw = bfly16_sum(psgw); psbw = bfly16_sum(psbw);
    if (lane == 0) { swred[wn][0] = psgw; swred[wn][1] = psbw; }  // wm dup benign

    // transform + per-row partial sums (per-ms pass bounds live registers)
#pragma unroll
    for (int ms = 0; ms < 2; ++ms) {
        float smc[4] = {}, sqc[4] = {}, sma[4] = {}, sqa[4] = {}, szgw[4] = {};
#pragma unroll
        for (int nt = 0; nt < 6; ++nt) {
#pragma unroll
            for (int reg = 0; reg < 4; ++reg) {
                const float val = acc[ms][nt][reg] + b_[nt];
                if (eC[nt]) {
                    const float zz = fmaxf(val, 0.f);
                    acc[ms][nt][reg] = zz;
                    smc[reg] += zz; sqc[reg] = fmaf(zz, zz, sqc[reg]);
                } else if (eA[nt]) {
                    const float za = ftanh(val);
                    sma[reg] += za; sqa[reg] = fmaf(za, za, sqa[reg]);
                    szgw[reg] = fmaf(za, gw[nt], szgw[reg]);
                }
            }
        }
#pragma unroll
        for (int reg = 0; reg < 4; ++reg) {
            smc[reg]  = bfly16_sum(smc[reg]);
            sqc[reg]  = bfly16_sum(sqc[reg]);
            sma[reg]  = bfly16_sum(sma[reg]);
            sqa[reg]  = bfly16_sum(sqa[reg]);
            szgw[reg] = bfly16_sum(szgw[reg]);
        }
        if (fr == 0) {
#pragma unroll
            for (int reg = 0; reg < 4; ++reg) {
                const int row = wm * 32 + ms * 16 + q * 4 + reg;
                *(f32x4*)&red[row][wn * 8] =
                    (f32x4){smc[reg], sqc[reg], sma[reg], sqa[reg]};
                red[row][wn * 8 + 4] = szgw[reg];
            }
        }
    }
    __syncthreads();   // red + swred + effacc-zero visible

    // wave0: per-row gate scalars (row = lane)
    if (wave == 0) {
        const float sgw = swred[0][0] + swred[1][0] + swred[2][0] + swred[3][0];
        const float ab2 = att_b2[0] +
            (swred[0][1] + swred[1][1] + swred[2][1] + swred[3][1]);
        const int rr = lane;
        float cj = 0.f, ag = 0.f, cm = 0.f;
        if (rr < nrows) {
            float s0 = 0.f, s1 = 0.f, s2 = 0.f, s3 = 0.f, s4 = 0.f;
#pragma unroll
            for (int w2 = 0; w2 < 4; ++w2) {
                const f32x4 v = *(const f32x4*)&red[rr][w2 * 8];
                s0 += v[0]; s1 += v[1]; s2 += v[2]; s3 += v[3];
                s4 += red[rr][w2 * 8 + 4];
            }
            const float muC = s0 * (1.f / H);
            const float rsC = __builtin_amdgcn_rsqf(s1 * (1.f / H) - muC * muC + EPS);
            const float muA = s2 * (1.f / HA);
            const float rsA = __builtin_amdgcn_rsqf(s3 * (1.f / HA) - muA * muA + EPS);
            const float dot = rsA * (s4 - muA * sgw) + ab2;
            ag = fsigmoid(dot);
            cj = ag * rsC;
            cm = cj * muC;
        }
        *(f32x4*)&scal[rr][0] = (f32x4){cj, ag, cm, 0.f};
    }
    __syncthreads();   // scal visible

    // gated accumulation into per-group effacc (LDS float atomics)
#pragma unroll
    for (int ms = 0; ms < 2; ++ms) {
#pragma unroll
        for (int reg = 0; reg < 4; ++reg) {
            const int row = wm * 32 + ms * 16 + q * 4 + reg;
            if (row >= nrows) continue;
            const float cj = scal[row][0];
            const int gbase = (row / 7) * 252;
#pragma unroll
            for (int nt = 0; nt < 6; ++nt) {
                if (!eC[nt]) continue;
                const int col = wn * 96 + nt * 16 + fr;
                unsafeAtomicAdd(&effacc[gbase + col], cj * acc[ms][nt][reg]);
            }
        }
    }
    // per-group scalar sums
    if (tid < NGB && tid < ngroups) {
        float a0 = 0.f, a1 = 0.f;
#pragma unroll
        for (int j = 0; j < 7; ++j) {
            a0 += scal[tid * 7 + j][1];
            a1 += scal[tid * 7 + j][2];
        }
        sS0[tid] = a0; sS1[tid] = a1;
    }
    __syncthreads();   // effacc + sS visible

    // write eff -> Abuf cols [250, 500)
    for (int i = tid; i < NGB * H; i += 512) {
        const int gl = i / H, col = i - gl * H;
        if (gl >= ngroups) break;
        const float o = ctx_g[col] * (effacc[gl * 252 + col] - sS1[gl])
                      + ctx_bt[col] * sS0[gl];
        Abuf[(size_t)(gb0 + gl) * KP + H + col] = f2bf(o);
    }
}

extern "C" void kernel_launch(void* const* d_in, const int* in_sizes, int n_in,
                              void* d_out, int out_size, void* d_ws, size_t ws_size,
                              hipStream_t stream)
{
    const float* x      = (const float*)d_in[0];
    const float* state  = (const float*)d_in[1];
    const float* enc_W  = (const float*)d_in[2];
    const float* enc_b  = (const float*)d_in[3];
    const float* enc_g  = (const float*)d_in[4];
    const float* enc_bt = (const float*)d_in[5];
    const float* core_W = (const float*)d_in[6];
    const float* core_b = (const float*)d_in[7];
    const float* core_g = (const float*)d_in[8];
    const float* core_bt= (const float*)d_in[9];
    const float* ctx_W  = (const float*)d_in[10];
    const float* ctx_b  = (const float*)d_in[11];
    const float* ctx_g  = (const float*)d_in[12];
    const float* ctx_bt = (const float*)d_in[13];
    const float* att_W1 = (const float*)d_in[14];
    const float* att_b1 = (const float*)d_in[15];
    const float* att_g  = (const float*)d_in[16];
    const float* att_bt = (const float*)d_in[17];
    const float* att_W2 = (const float*)d_in[18];
    const float* att_b2 = (const float*)d_in[19];
    const float* out_W  = (const float*)d_in[20];
    const float* out_b  = (const float*)d_in[21];
    float* out = (float*)d_out;

    // workspace layout (ushort units) — Cs eliminated; Co kept
    ushort_t* Abuf = (ushort_t*)d_ws;                   // 16384*1088  (35.7 MB)
    ushort_t* Wt   = Abuf + (size_t)ROWS * KP;          // 256*1088
    ushort_t* Wpq  = Wt + (size_t)256 * KP;             // 512*256
    ushort_t* Wca  = Wpq + (size_t)512 * 256;           // 384*256
    ushort_t* Wenc = Wca + (size_t)384 * 256;           // 256*256
    ushort_t* Co   = Wenc + (size_t)256 * 256;          // 114688*256  (58.7 MB)
    ushort_t* Sb   = Co + (size_t)PROWS * 256;          // 16384*256   (8 MB)
    ushort_t* Epre = Sb + (size_t)ROWS * 256;           // 16384*256   (8 MB)
    ushort_t* PQb  = Epre + (size_t)ROWS * 256;         // 16384*512   (16 MB)

    k_prep  <<<2432 + ROWS, 256, 0, stream>>>(out_W, core_W, ctx_W, att_W1, enc_W,
                                              state, x, Wt, Wpq, Wca, Wenc, Sb, Abuf);
    // Epre = state @ enc_W  (bf16 MFMA, N=256 resident)
    k_gemm_nres<4><<<ROWS / 64, 512, 0, stream>>>(Sb, 256, Wenc, 256, Epre, 256,
                                                  nullptr, 8, 256, 1);
    k_lnenc <<<ROWS / 4, 256, 0, stream>>>(Epre, enc_b, enc_g, enc_bt, Abuf);
    // PQb = s1 @ [W_top | W_bot]  (bf16 MFMA, N=512 resident, bf16 out)
    k_gemm_nres<8><<<ROWS / 64, 512, 0, stream>>>(Abuf, KP, Wpq, 256, PQb, PQS,
                                                  nullptr, 8, 512, 1);
    k_core  <<<ROWS / 4, 256, 0, stream>>>(PQb, core_b, core_g, core_bt, Co);
    // fused cs+eff: 9 groups per block
    k_cseff <<<(ROWS + NGB - 1) / NGB, 512, 0, stream>>>(Co, Wca,
                                            ctx_b, ctx_g, ctx_bt,
                                            att_b1, att_g, att_bt,
                                            att_W2, att_b2, Abuf);
    // out = [s1 | eff | x] @ out_W + b  (bf16 MFMA, N=256 resident, fp32 out)
    k_gemm_nres<4><<<ROWS / 64, 512, 0, stream>>>(Abuf, KP, Wt, KP, out, H,
                                                  out_b, KP / 32, 250, 0);
}

// Round 8
// 339.826 us; speedup vs baseline: 1.3176x; 1.3176x over previous
//
#include <hip/hip_runtime.h>
#include <math.h>

#define KK 8
#define H 250          // SIZE == h1
#define MDIM 576
#define NB 2048
#define HA 100
#define ROWS (NB*KK)   // 16384
#define PROWS (ROWS*7) // 114688 pair rows
#define PQS 512        // PQb row stride (ushort): P at 0..249, Q at 256..505
#define KP 1088        // padded K for out GEMM (1076 -> 34*32)
#define EPS 1e-5f

typedef unsigned short ushort_t;
typedef short short8 __attribute__((ext_vector_type(8)));
typedef unsigned short us8 __attribute__((ext_vector_type(8)));
typedef unsigned short us4 __attribute__((ext_vector_type(4)));
typedef unsigned short us2 __attribute__((ext_vector_type(2)));
typedef float f32x4 __attribute__((ext_vector_type(4)));

// ---- DPP helpers (old=0 + bound_ctrl=1 so GCNDPPCombine folds to v_add_f32_dpp) ----
template<int CTRL>
__device__ __forceinline__ float dpp_add_f32(float x) {
    const int s = __builtin_amdgcn_update_dpp(
        0, __builtin_bit_cast(int, x), CTRL, 0xF, 0xF, true);
    return x + __builtin_bit_cast(float, s);
}
// full-wave (64-lane) sum; result broadcast wave-uniform via readlane(63)
__device__ __forceinline__ float wave_sum_dpp(float x) {
    x = dpp_add_f32<0x111>(x);  // row_shr:1
    x = dpp_add_f32<0x112>(x);  // row_shr:2
    x = dpp_add_f32<0x114>(x);  // row_shr:4
    x = dpp_add_f32<0x118>(x);  // row_shr:8
    x = dpp_add_f32<0x142>(x);  // row_bcast:15
    x = dpp_add_f32<0x143>(x);  // row_bcast:31 -> lane 63 holds total
    return __builtin_bit_cast(float, __builtin_amdgcn_readlane(
        __builtin_bit_cast(int, x), 63));
}
// 16-lane butterfly sum: result present in ALL 16 lanes of each 16-lane row
__device__ __forceinline__ float bfly16_sum(float x) {
    x = dpp_add_f32<0xB1>(x);   // quad_perm [1,0,3,2]  (xor 1)
    x = dpp_add_f32<0x4E>(x);   // quad_perm [2,3,0,1]  (xor 2)
    x = dpp_add_f32<0x141>(x);  // row_half_mirror      (pairs across quads)
    x = dpp_add_f32<0x140>(x);  // row_mirror           (pairs across halves)
    return x;
}

__device__ __forceinline__ void async_copy16(const void* g, void* l) {
    __builtin_amdgcn_global_load_lds(
        (const __attribute__((address_space(1))) void*)g,
        (__attribute__((address_space(3))) void*)l, 16, 0, 0);
}

__device__ __forceinline__ ushort_t f2bf(float v) {
    union { float f; unsigned int u; } c; c.f = v;
    unsigned int x = c.u;
    x += 0x7fff + ((x >> 16) & 1);   // RNE
    return (ushort_t)(x >> 16);
}
__device__ __forceinline__ float bf2f(ushort_t v) {
    union { unsigned int u; float f; } c; c.u = ((unsigned int)v) << 16;
    return c.f;
}
// fast tanh: 1 - 2/(exp(2x)+1)  (v_exp + v_rcp; ~1e-6 rel err, << bf16 ulp)
__device__ __forceinline__ float ftanh(float x) {
    const float e = __expf(2.f * x);
    return 1.f - 2.f * __builtin_amdgcn_rcpf(e + 1.f);
}
__device__ __forceinline__ float fsigmoid(float x) {
    return __builtin_amdgcn_rcpf(1.f + __expf(-x));
}

// ---- fused prep: Wt | Wpq | Wca | Wenc | Sb | x->Abuf (16 rows/block) ----
__global__ __launch_bounds__(256) void k_prep(
    const float* __restrict__ out_W, const float* __restrict__ core_W,
    const float* __restrict__ ctx_W, const float* __restrict__ att_W1,
    const float* __restrict__ enc_W, const float* __restrict__ state,
    const float* __restrict__ x,
    ushort_t* __restrict__ Wt, ushort_t* __restrict__ Wpq,
    ushort_t* __restrict__ Wca, ushort_t* __restrict__ Wenc,
    ushort_t* __restrict__ Sb, ushort_t* __restrict__ Abuf)
{
    const int b = blockIdx.x, t = threadIdx.x;
    if (b < 256) {                      // Wt[n][k] = out_W[k][n]
        const int n = b;
        for (int k = t; k < KP; k += 256) {
            const float v = (n < H && k < 1076) ? out_W[(size_t)k * H + n] : 0.f;
            Wt[(size_t)n * KP + k] = f2bf(v);
        }
    } else if (b < 768) {               // Wpq
        const int n = b - 256, k = t;
        float v = 0.f;
        if (k < H) {
            if (n < H)                    v = core_W[(size_t)k * H + n];
            else if (n >= 256 && n < 506) v = core_W[(size_t)(H + k) * H + (n - 256)];
        }
        Wpq[(size_t)n * 256 + k] = f2bf(v);
    } else if (b < 1152) {              // Wca
        const int n = b - 768, k = t;
        float v = 0.f;
        if (k < H) {
            if (n < H)           v = ctx_W[(size_t)k * H + n];
            else if (n < H + HA) v = att_W1[(size_t)k * HA + (n - H)];
        }
        Wca[(size_t)n * 256 + k] = f2bf(v);
    } else if (b < 1408) {              // Wenc[n][k] = enc_W[k][n]
        const int n = b - 1152, k = t;
        const float v = (n < H && k < H) ? enc_W[(size_t)k * H + n] : 0.f;
        Wenc[(size_t)n * 256 + k] = f2bf(v);
    } else if (b < 2432) {              // Sb: state padded to 256, bf16
        const int r0 = (b - 1408) * 16;
        for (int idx = t; idx < 16 * 256; idx += 256) {
            const int r = r0 + (idx >> 8), k = idx & 255;
            const float v = (k < H) ? state[(size_t)r * H + k] : 0.f;
            Sb[(size_t)r * 256 + k] = f2bf(v);
        }
    } else {                            // Abuf cols [500,1088): x + pad, 16 rows/block
        const int r0 = (b - 2432) * 16;
        for (int idx = t; idx < 16 * 588; idx += 256) {
            const int r = r0 + idx / 588, c = 500 + idx % 588;
            const float v = (c < 500 + MDIM) ? x[(size_t)r * MDIM + (c - 500)] : 0.f;
            Abuf[(size_t)r * KP + c] = f2bf(v);
        }
    }
}

// N-resident bf16 MFMA GEMM (k_cs-style): C[m][n] = sum_k A[m][k]*B[n][k] (+bias)
// Whole N = NT*64 resident in LDS per block -> A fetched exactly once.
// 512 thr = 8 waves (2m x 4n); per wave 32 rows x NT*16 cols; acc[2][NT].
template<int NT>
__global__ __launch_bounds__(512, NT == 8 ? 2 : 4) void k_gemm_nres(
    const ushort_t* __restrict__ A, int lda,
    const ushort_t* __restrict__ B, int ldb,
    void* __restrict__ Cp, int ldc,
    const float* __restrict__ bias,
    int ksteps, int nlim, int bf16out)
{
    constexpr int NROWS = NT * 64;                    // B rows resident
    __shared__ __align__(16) ushort_t As[64 * 32];    // 4 KB
    __shared__ __align__(16) ushort_t Bs[NROWS * 32]; // NT*4 KB
    const int tid = threadIdx.x, lane = tid & 63, wave = tid >> 6;
    const int wm = wave >> 2, wn = wave & 3;
    const int R0 = (int)blockIdx.x * 64;

    const int ar = tid >> 2, acb = tid & 3;
    const bool aon = tid < 256;
    const int acl = acb ^ ((ar >> 1) & 3);
    const ushort_t* gA = A + (size_t)(R0 + ar) * lda + acl * 8;

    const int q = lane >> 4, fr = lane & 15;

    f32x4 acc[2][NT] = {};
    for (int ks = 0; ks < ksteps; ++ks) {
        const int k0 = ks * 32;
        if (aon) async_copy16(gA + k0, &As[tid * 8]);
#pragma unroll
        for (int it = 0; it < NT / 2; ++it) {
            const int ci  = it * 512 + tid;
            const int rb  = ci >> 2, cb2 = ci & 3;
            const int clb = cb2 ^ ((rb >> 1) & 3);
            async_copy16(B + (size_t)rb * ldb + k0 + clb * 8, &Bs[ci * 8]);
        }
        __syncthreads();
        short8 a[2];
#pragma unroll
        for (int ms = 0; ms < 2; ++ms) {
            const int row = wm * 32 + ms * 16 + fr;
            a[ms] = *(const short8*)&As[(row * 4 + (q ^ ((row >> 1) & 3))) * 8];
        }
#pragma unroll
        for (int nt = 0; nt < NT; ++nt) {
            const int n = wn * (NT * 16) + nt * 16 + fr;
            const short8 b = *(const short8*)&Bs[(n * 4 + (q ^ ((n >> 1) & 3))) * 8];
#pragma unroll
            for (int ms = 0; ms < 2; ++ms)
                acc[ms][nt] = __builtin_amdgcn_mfma_f32_16x16x32_bf16(
                    a[ms], b, acc[ms][nt], 0, 0, 0);
        }
        __syncthreads();
    }

#pragma unroll
    for (int ms = 0; ms < 2; ++ms)
#pragma unroll
        for (int nt = 0; nt < NT; ++nt) {
            const int col = wn * (NT * 16) + nt * 16 + fr;
            if (col >= nlim) continue;
            const float bv = bias ? bias[col] : 0.f;
#pragma unroll
            for (int reg = 0; reg < 4; ++reg) {
                const int row = R0 + wm * 32 + ms * 16 + q * 4 + reg;
                const float v = acc[ms][nt][reg] + bv;
                if (bf16out) ((ushort_t*)Cp)[(size_t)row * ldc + col] = f2bf(v);
                else         ((float*)Cp)[(size_t)row * ldc + col] = v;
            }
        }
}

// LN(relu(Epre + enc_b)) -> Abuf cols [0,250). One wave per row, us4 loads.
__global__ __launch_bounds__(256) void k_lnenc(const ushort_t* __restrict__ Epre,
    const float* __restrict__ eb, const float* __restrict__ eg,
    const float* __restrict__ ebt, ushort_t* __restrict__ Abuf)
{
    const int wave = threadIdx.x >> 6, lane = threadIdx.x & 63;
    const int row = blockIdx.x * 4 + wave;
    const int c0 = 4 * lane;

    const us4 v = *(const us4*)&Epre[(size_t)row * 256 + c0];
    float y[4]; float sm = 0.f, sq = 0.f;
#pragma unroll
    for (int t = 0; t < 4; ++t) {
        const int cc = c0 + t;
        float z = 0.f;
        if (cc < H) z = fmaxf(bf2f(v[t]) + eb[cc], 0.f);
        y[t] = z; sm += z; sq += z * z;
    }
    sm = wave_sum_dpp(sm);
    sq = wave_sum_dpp(sq);
    const float mu = sm * (1.f / H);
    const float rs = __builtin_amdgcn_rsqf(sq * (1.f / H) - mu * mu + EPS);
    ushort_t o[4];
#pragma unroll
    for (int t = 0; t < 4; ++t) {
        const int cc = c0 + t;
        o[t] = (cc < H) ? f2bf((y[t] - mu) * rs * eg[cc] + ebt[cc]) : (ushort_t)0;
    }
    ushort_t* dst = Abuf + (size_t)row * KP + c0;
    if (c0 + 3 < H) { *(us4*)dst = (us4){o[0], o[1], o[2], o[3]}; }
    else {
        if (c0 + 1 < H) *(us2*)dst = (us2){o[0], o[1]};
    }
}

// Co[r][0:256] = LN(relu(P_g + Q_qr + core_b)) bf16. One wave per GROUP.
__global__ __launch_bounds__(256) void k_core(const ushort_t* __restrict__ PQb,
    const float* __restrict__ core_b, const float* __restrict__ core_g,
    const float* __restrict__ core_bt, ushort_t* __restrict__ Co)
{
    const int wave = threadIdx.x >> 6, lane = threadIdx.x & 63;
    const int g = blockIdx.x * 4 + wave;        // group 0..16383
    const int i = g & 7;
    const int c = lane * 4;

    const us4 pu = *(const us4*)&PQb[(size_t)g * PQS + c];
    us4 qu[7];
#pragma unroll
    for (int jj = 0; jj < 7; ++jj) {
        const int j = jj + (jj >= i ? 1 : 0);
        const int qr = (g & ~7) + j;
        qu[jj] = *(const us4*)&PQb[(size_t)qr * PQS + 256 + c];
    }
    float pe[4], cb[4], cg[4], cbt[4]; bool vl[4];
#pragma unroll
    for (int t = 0; t < 4; ++t) {
        vl[t]  = (c + t) < H;
        pe[t]  = bf2f(pu[t]);
        cb[t]  = vl[t] ? core_b[c + t]  : 0.f;
        cg[t]  = vl[t] ? core_g[c + t]  : 0.f;
        cbt[t] = vl[t] ? core_bt[c + t] : 0.f;
    }
    float z[7][4], red[7][2];
#pragma unroll
    for (int jj = 0; jj < 7; ++jj) {
        float sm = 0.f, sq = 0.f;
#pragma unroll
        for (int t = 0; t < 4; ++t) {
            const float zz = vl[t] ? fmaxf(pe[t] + bf2f(qu[jj][t]) + cb[t], 0.f) : 0.f;
            z[jj][t] = zz; sm += zz; sq = fmaf(zz, zz, sq);
        }
        red[jj][0] = sm; red[jj][1] = sq;
    }
#pragma unroll
    for (int jj = 0; jj < 7; ++jj) {
        red[jj][0] = wave_sum_dpp(red[jj][0]);
        red[jj][1] = wave_sum_dpp(red[jj][1]);
    }
#pragma unroll
    for (int jj = 0; jj < 7; ++jj) {
        const float mu = red[jj][0] * (1.f / H);
        const float rs = __builtin_amdgcn_rsqf(red[jj][1] * (1.f / H) - mu * mu + EPS);
        us4 o;
#pragma unroll
        for (int t = 0; t < 4; ++t)
            o[t] = vl[t] ? f2bf((z[jj][t] - mu) * rs * cg[t] + cbt[t]) : (ushort_t)0;
        *(us4*)&Co[((size_t)g * 7 + jj) * 256 + c] = o;
    }
}

// ================= k_cs: GEMM + register-only stats epilogue =================
// GEMM identical to r1 k_cs (LDS 28.6 KB, 5 blocks/CU — DO NOT add LDS here;
// r7 proved +20KB LDS/barriers collapses this latency-bound kernel 46->218us).
// Epilogue (regs + bfly16 only): writes post-relu ctx z to Cs[row][256] and
// per-(row,wn) partial stats {smc,sqc,sma,sqa,szgw} to Srow[row][wn*8..].
__global__ __launch_bounds__(512, 4) void k_cs(
    const ushort_t* __restrict__ Co,
    const ushort_t* __restrict__ Wca,   // [384][256] bf16
    const float* __restrict__ ctx_b,
    const float* __restrict__ att_b1, const float* __restrict__ att_g,
    const float* __restrict__ attW2,
    ushort_t* __restrict__ Cs, float* __restrict__ Srow)
{
    __shared__ __align__(16) ushort_t As[64 * 32];    // 4096 B
    __shared__ __align__(16) ushort_t Bs[384 * 32];   // 24576 B
    const int tid = threadIdx.x, lane = tid & 63, wave = tid >> 6;
    const int wm = wave >> 1, wn = wave & 1;  // placeholder (unused mapping)
    (void)wm; (void)wn;
    const int wmm = wave >> 2, wnn = wave & 3;
    const int R0 = (int)blockIdx.x * 64;

    const int ar = tid >> 2, acb = tid & 3;
    const bool aon = tid < 256;
    const int acl = acb ^ ((ar >> 1) & 3);
    const ushort_t* gA = Co + (size_t)(R0 + ar) * 256 + acl * 8;

    const int q = lane >> 4, fr = lane & 15;

    f32x4 acc[2][6] = {};
    for (int ks = 0; ks < 8; ++ks) {
        const int k0 = ks * 32;
        if (aon) async_copy16(gA + k0, &As[tid * 8]);
#pragma unroll
        for (int it = 0; it < 3; ++it) {
            const int ci  = it * 512 + tid;
            const int rb  = ci >> 2, cb2 = ci & 3;
            const int clb = cb2 ^ ((rb >> 1) & 3);
            async_copy16(Wca + (size_t)rb * 256 + k0 + clb * 8, &Bs[ci * 8]);
        }
        __syncthreads();
        short8 a[2];
#pragma unroll
        for (int ms = 0; ms < 2; ++ms) {
            const int row = wmm * 32 + ms * 16 + fr;
            a[ms] = *(const short8*)&As[(row * 4 + (q ^ ((row >> 1) & 3))) * 8];
        }
#pragma unroll
        for (int nt = 0; nt < 6; ++nt) {
            const int n = wnn * 96 + nt * 16 + fr;
            const short8 b = *(const short8*)&Bs[(n * 4 + (q ^ ((n >> 1) & 3))) * 8];
#pragma unroll
            for (int ms = 0; ms < 2; ++ms)
                acc[ms][nt] = __builtin_amdgcn_mfma_f32_16x16x32_bf16(
                    a[ms], b, acc[ms][nt], 0, 0, 0);
        }
        __syncthreads();
    }

    // ---- epilogue: per-col consts (loaded now; keeps GEMM regs unchanged) ----
    bool eC[6], eA[6]; float b_[6], gw[6];
#pragma unroll
    for (int nt = 0; nt < 6; ++nt) {
        const int col = wnn * 96 + nt * 16 + fr;
        eC[nt] = col < H;
        eA[nt] = (col >= H) && (col < H + HA);
        if (eC[nt])      { b_[nt] = ctx_b[col];      gw[nt] = 0.f; }
        else if (eA[nt]) { const int ca = col - H;
                           b_[nt] = att_b1[ca];
                           gw[nt] = att_g[ca] * attW2[ca]; }
        else             { b_[nt] = gw[nt] = 0.f; }
    }

    // per-ms pass bounds live registers (r7-proven transform, minus LDS use)
#pragma unroll
    for (int ms = 0; ms < 2; ++ms) {
        float smc[4] = {}, sqc[4] = {}, sma[4] = {}, sqa[4] = {}, szgw[4] = {};
#pragma unroll
        for (int nt = 0; nt < 6; ++nt) {
#pragma unroll
            for (int reg = 0; reg < 4; ++reg) {
                const float val = acc[ms][nt][reg] + b_[nt];
                if (eC[nt]) {
                    const float zz = fmaxf(val, 0.f);
                    acc[ms][nt][reg] = zz;
                    smc[reg] += zz; sqc[reg] = fmaf(zz, zz, sqc[reg]);
                } else if (eA[nt]) {
                    const float za = ftanh(val);
                    sma[reg] += za; sqa[reg] = fmaf(za, za, sqa[reg]);
                    szgw[reg] = fmaf(za, gw[nt], szgw[reg]);
                }
            }
        }
#pragma unroll
        for (int reg = 0; reg < 4; ++reg) {
            smc[reg]  = bfly16_sum(smc[reg]);
            sqc[reg]  = bfly16_sum(sqc[reg]);
            sma[reg]  = bfly16_sum(sma[reg]);
            sqa[reg]  = bfly16_sum(sqa[reg]);
            szgw[reg] = bfly16_sum(szgw[reg]);
        }
        if (fr == 0) {
#pragma unroll
            for (int reg = 0; reg < 4; ++reg) {
                const int row = R0 + wmm * 32 + ms * 16 + q * 4 + reg;
                *(f32x4*)&Srow[(size_t)row * 32 + wnn * 8] =
                    (f32x4){smc[reg], sqc[reg], sma[reg], sqa[reg]};
                Srow[(size_t)row * 32 + wnn * 8 + 4] = szgw[reg];
            }
        }
        // write z (relu'd ctx) to Cs cols [0,256); att cols 250..255 get 0
#pragma unroll
        for (int nt = 0; nt < 6; ++nt) {
            const int col = wnn * 96 + nt * 16 + fr;
            if (col >= 256) continue;
#pragma unroll
            for (int reg = 0; reg < 4; ++reg) {
                const int row = R0 + wmm * 32 + ms * 16 + q * 4 + reg;
                Cs[(size_t)row * 256 + col] =
                    eC[nt] ? f2bf(acc[ms][nt][reg]) : (ushort_t)0;
            }
        }
    }
}

// ================= k_eff2: fold partials + gate + weighted sum =================
// One wave per group. Pure streaming: reads 7x256 z (bf16) + 7x20 scalars,
// no tanh/transform/35-chain reduction (moved into k_cs's register epilogue).
__global__ __launch_bounds__(256) void k_eff2(
    const ushort_t* __restrict__ Cs, const float* __restrict__ Srow,
    const float* __restrict__ ctx_g, const float* __restrict__ ctx_bt,
    const float* __restrict__ att_g, const float* __restrict__ att_bt,
    const float* __restrict__ attW2, const float* __restrict__ att_b2,
    ushort_t* __restrict__ Abuf)
{
    const int wave = threadIdx.x >> 6, lane = threadIdx.x & 63;
    const int g = blockIdx.x * 4 + wave;
    const int c0 = 4 * lane;

    // row-invariant attention sums
    float psg = 0.f, psb = 0.f;
    for (int c = lane; c < HA; c += 64) {
        const float w2 = attW2[c];
        psg = fmaf(att_g[c], w2, psg);
        psb = fmaf(att_bt[c], w2, psb);
    }
    psg = wave_sum_dpp(psg); psb = wave_sum_dpp(psb);
    const float sgw = psg;
    const float ab2 = att_b2[0] + psb;

    float g4[4], bt4[4];
#pragma unroll
    for (int t = 0; t < 4; ++t) {
        const bool vl = (c0 + t) < H;
        g4[t]  = vl ? ctx_g[c0 + t]  : 0.f;
        bt4[t] = vl ? ctx_bt[c0 + t] : 0.f;
    }

    // prefetch z rows
    us4 zv[7];
#pragma unroll
    for (int jj = 0; jj < 7; ++jj)
        zv[jj] = *(const us4*)&Cs[((size_t)g * 7 + jj) * 256 + c0];

    float A4[4] = {0.f, 0.f, 0.f, 0.f};
    float S0 = 0.f, S1 = 0.f;
#pragma unroll
    for (int jj = 0; jj < 7; ++jj) {
        const float* sr = Srow + ((size_t)g * 7 + jj) * 32;
        float s0 = 0.f, s1 = 0.f, s2 = 0.f, s3 = 0.f, s4 = 0.f;
#pragma unroll
        for (int w = 0; w < 4; ++w) {
            const f32x4 v = *(const f32x4*)&sr[w * 8];
            s0 += v[0]; s1 += v[1]; s2 += v[2]; s3 += v[3];
            s4 += sr[w * 8 + 4];
        }
        const float muC = s0 * (1.f / H);
        const float rsC = __builtin_amdgcn_rsqf(s1 * (1.f / H) - muC * muC + EPS);
        const float muA = s2 * (1.f / HA);
        const float rsA = __builtin_amdgcn_rsqf(s3 * (1.f / HA) - muA * muA + EPS);
        const float dot = rsA * (s4 - muA * sgw) + ab2;
        const float ag  = fsigmoid(dot);
        const float cj  = ag * rsC;
        S0 += ag; S1 = fmaf(cj, muC, S1);
#pragma unroll
        for (int e = 0; e < 4; ++e)
            A4[e] = fmaf(cj, bf2f(zv[jj][e]), A4[e]);
    }
    ushort_t o[4];
#pragma unroll
    for (int e = 0; e < 4; ++e)
        o[e] = f2bf(g4[e] * (A4[e] - S1) + bt4[e] * S0);
    ushort_t* dst = Abuf + (size_t)g * KP + H + c0;
    if (c0 + 1 < H) *(us2*)dst       = (us2){o[0], o[1]};
    if (c0 + 3 < H) *(us2*)(dst + 2) = (us2){o[2], o[3]};
}

extern "C" void kernel_launch(void* const* d_in, const int* in_sizes, int n_in,
                              void* d_out, int out_size, void* d_ws, size_t ws_size,
                              hipStream_t stream)
{
    const float* x      = (const float*)d_in[0];
    const float* state  = (const float*)d_in[1];
    const float* enc_W  = (const float*)d_in[2];
    const float* enc_b  = (const float*)d_in[3];
    const float* enc_g  = (const float*)d_in[4];
    const float* enc_bt = (const float*)d_in[5];
    const float* core_W = (const float*)d_in[6];
    const float* core_b = (const float*)d_in[7];
    const float* core_g = (const float*)d_in[8];
    const float* core_bt= (const float*)d_in[9];
    const float* ctx_W  = (const float*)d_in[10];
    const float* ctx_b  = (const float*)d_in[11];
    const float* ctx_g  = (const float*)d_in[12];
    const float* ctx_bt = (const float*)d_in[13];
    const float* att_W1 = (const float*)d_in[14];
    const float* att_b1 = (const float*)d_in[15];
    const float* att_g  = (const float*)d_in[16];
    const float* att_bt = (const float*)d_in[17];
    const float* att_W2 = (const float*)d_in[18];
    const float* att_b2 = (const float*)d_in[19];
    const float* out_W  = (const float*)d_in[20];
    const float* out_b  = (const float*)d_in[21];
    float* out = (float*)d_out;

    // layout (ushort units); Sb/Epre/PQb alias the Cs region (dead before k_cs)
    ushort_t* Abuf = (ushort_t*)d_ws;                   // 16384*1088      (35.7 MB)
    ushort_t* Wt   = Abuf + (size_t)ROWS * KP;          // 256*1088
    ushort_t* Wpq  = Wt + (size_t)256 * KP;             // 512*256
    ushort_t* Wca  = Wpq + (size_t)512 * 256;           // 384*256
    ushort_t* Wenc = Wca + (size_t)384 * 256;           // 256*256
    ushort_t* Co   = Wenc + (size_t)256 * 256;          // 114688*256     (58.7 MB)
    ushort_t* Cs   = Co + (size_t)PROWS * 256;          // 114688*256     (58.7 MB)
    float*    Srow = (float*)(Cs + (size_t)PROWS * 256);// 114688*32 f32  (14.7 MB)
    ushort_t* Sb   = Cs;                                // 16384*256  (aliased)
    ushort_t* Epre = Sb + (size_t)ROWS * 256;           // 16384*256  (aliased)
    ushort_t* PQb  = Epre + (size_t)ROWS * 256;         // 16384*512  (aliased)

    k_prep  <<<3456, 256, 0, stream>>>(out_W, core_W, ctx_W, att_W1, enc_W,
                                       state, x, Wt, Wpq, Wca, Wenc, Sb, Abuf);
    // Epre = state @ enc_W  (bf16 MFMA, N=256 resident)
    k_gemm_nres<4><<<ROWS / 64, 512, 0, stream>>>(Sb, 256, Wenc, 256, Epre, 256,
                                                  nullptr, 8, 256, 1);
    k_lnenc <<<ROWS / 4, 256, 0, stream>>>(Epre, enc_b, enc_g, enc_bt, Abuf);
    // PQb = s1 @ [W_top | W_bot]  (bf16 MFMA, N=512 resident, bf16 out)
    k_gemm_nres<8><<<ROWS / 64, 512, 0, stream>>>(Abuf, KP, Wpq, 256, PQb, PQS,
                                                  nullptr, 8, 512, 1);
    k_core  <<<ROWS / 4, 256, 0, stream>>>(PQb, core_b, core_g, core_bt, Co);
    // GEMM + stats epilogue (z -> Cs, partial stats -> Srow)
    k_cs    <<<PROWS / 64, 512, 0, stream>>>(Co, Wca, ctx_b, att_b1, att_g,
                                             att_W2, Cs, Srow);
    // fold partials + gate + weighted sum -> eff
    k_eff2  <<<ROWS / 4, 256, 0, stream>>>(Cs, Srow, ctx_g, ctx_bt,
                                           att_g, att_bt, att_W2, att_b2, Abuf);
    // out = [s1 | eff | x] @ out_W + b  (bf16 MFMA, N=256 resident, fp32 out)
    k_gemm_nres<4><<<ROWS / 64, 512, 0, stream>>>(Abuf, KP, Wt, KP, out, H,
                                                  out_b, KP / 32, 250, 0);
}

// Round 10
// 337.448 us; speedup vs baseline: 1.3269x; 1.0070x over previous
//
#include <hip/hip_runtime.h>
#include <math.h>

#define KK 8
#define H 250          // SIZE == h1
#define MDIM 576
#define NB 2048
#define HA 100
#define ROWS (NB*KK)   // 16384
#define PROWS (ROWS*7) // 114688 pair rows
#define PQS 512        // PQb row stride (ushort): P at 0..249, Q at 256..505
#define KP 1088        // padded K for out GEMM (1076 -> 34*32)
#define EPS 1e-5f

typedef unsigned short ushort_t;
typedef short short8 __attribute__((ext_vector_type(8)));
typedef unsigned short us8 __attribute__((ext_vector_type(8)));
typedef unsigned short us4 __attribute__((ext_vector_type(4)));
typedef unsigned short us2 __attribute__((ext_vector_type(2)));
typedef float f32x4 __attribute__((ext_vector_type(4)));

// ---- DPP helpers (old=0 + bound_ctrl=1 so GCNDPPCombine folds to v_add_f32_dpp) ----
template<int CTRL>
__device__ __forceinline__ float dpp_add_f32(float x) {
    const int s = __builtin_amdgcn_update_dpp(
        0, __builtin_bit_cast(int, x), CTRL, 0xF, 0xF, true);
    return x + __builtin_bit_cast(float, s);
}
// full-wave (64-lane) sum; result broadcast wave-uniform via readlane(63)
__device__ __forceinline__ float wave_sum_dpp(float x) {
    x = dpp_add_f32<0x111>(x);  // row_shr:1
    x = dpp_add_f32<0x112>(x);  // row_shr:2
    x = dpp_add_f32<0x114>(x);  // row_shr:4
    x = dpp_add_f32<0x118>(x);  // row_shr:8
    x = dpp_add_f32<0x142>(x);  // row_bcast:15
    x = dpp_add_f32<0x143>(x);  // row_bcast:31 -> lane 63 holds total
    return __builtin_bit_cast(float, __builtin_amdgcn_readlane(
        __builtin_bit_cast(int, x), 63));
}
// 16-lane butterfly sum: result present in ALL 16 lanes of each 16-lane row
__device__ __forceinline__ float bfly16_sum(float x) {
    x = dpp_add_f32<0xB1>(x);   // quad_perm [1,0,3,2]  (xor 1)
    x = dpp_add_f32<0x4E>(x);   // quad_perm [2,3,0,1]  (xor 2)
    x = dpp_add_f32<0x141>(x);  // row_half_mirror      (pairs across quads)
    x = dpp_add_f32<0x140>(x);  // row_mirror           (pairs across halves)
    return x;
}

__device__ __forceinline__ void async_copy16(const void* g, void* l) {
    __builtin_amdgcn_global_load_lds(
        (const __attribute__((address_space(1))) void*)g,
        (__attribute__((address_space(3))) void*)l, 16, 0, 0);
}

__device__ __forceinline__ ushort_t f2bf(float v) {
    union { float f; unsigned int u; } c; c.f = v;
    unsigned int x = c.u;
    x += 0x7fff + ((x >> 16) & 1);   // RNE
    return (ushort_t)(x >> 16);
}
__device__ __forceinline__ float bf2f(ushort_t v) {
    union { unsigned int u; float f; } c; c.u = ((unsigned int)v) << 16;
    return c.f;
}
// fast tanh: 1 - 2/(exp(2x)+1)  (v_exp + v_rcp; ~1e-6 rel err, << bf16 ulp)
__device__ __forceinline__ float ftanh(float x) {
    const float e = __expf(2.f * x);
    return 1.f - 2.f * __builtin_amdgcn_rcpf(e + 1.f);
}
__device__ __forceinline__ float fsigmoid(float x) {
    return __builtin_amdgcn_rcpf(1.f + __expf(-x));
}

// ---- fused prep: Wt | Wpq | Wca | Wenc | Sb | x->Abuf (16 rows/block) ----
__global__ __launch_bounds__(256) void k_prep(
    const float* __restrict__ out_W, const float* __restrict__ core_W,
    const float* __restrict__ ctx_W, const float* __restrict__ att_W1,
    const float* __restrict__ enc_W, const float* __restrict__ state,
    const float* __restrict__ x,
    ushort_t* __restrict__ Wt, ushort_t* __restrict__ Wpq,
    ushort_t* __restrict__ Wca, ushort_t* __restrict__ Wenc,
    ushort_t* __restrict__ Sb, ushort_t* __restrict__ Abuf)
{
    const int b = blockIdx.x, t = threadIdx.x;
    if (b < 256) {                      // Wt[n][k] = out_W[k][n]
        const int n = b;
        for (int k = t; k < KP; k += 256) {
            const float v = (n < H && k < 1076) ? out_W[(size_t)k * H + n] : 0.f;
            Wt[(size_t)n * KP + k] = f2bf(v);
        }
    } else if (b < 768) {               // Wpq
        const int n = b - 256, k = t;
        float v = 0.f;
        if (k < H) {
            if (n < H)                    v = core_W[(size_t)k * H + n];
            else if (n >= 256 && n < 506) v = core_W[(size_t)(H + k) * H + (n - 256)];
        }
        Wpq[(size_t)n * 256 + k] = f2bf(v);
    } else if (b < 1152) {              // Wca
        const int n = b - 768, k = t;
        float v = 0.f;
        if (k < H) {
            if (n < H)           v = ctx_W[(size_t)k * H + n];
            else if (n < H + HA) v = att_W1[(size_t)k * HA + (n - H)];
        }
        Wca[(size_t)n * 256 + k] = f2bf(v);
    } else if (b < 1408) {              // Wenc[n][k] = enc_W[k][n]
        const int n = b - 1152, k = t;
        const float v = (n < H && k < H) ? enc_W[(size_t)k * H + n] : 0.f;
        Wenc[(size_t)n * 256 + k] = f2bf(v);
    } else if (b < 2432) {              // Sb: state padded to 256, bf16
        const int r0 = (b - 1408) * 16;
        for (int idx = t; idx < 16 * 256; idx += 256) {
            const int r = r0 + (idx >> 8), k = idx & 255;
            const float v = (k < H) ? state[(size_t)r * H + k] : 0.f;
            Sb[(size_t)r * 256 + k] = f2bf(v);
        }
    } else {                            // Abuf cols [500,1088): x + pad, 16 rows/block
        const int r0 = (b - 2432) * 16;
        for (int idx = t; idx < 16 * 588; idx += 256) {
            const int r = r0 + idx / 588, c = 500 + idx % 588;
            const float v = (c < 500 + MDIM) ? x[(size_t)r * MDIM + (c - 500)] : 0.f;
            Abuf[(size_t)r * KP + c] = f2bf(v);
        }
    }
}

// N-resident bf16 MFMA GEMM: C[m][n] = sum_k A[m][k]*B[n][k] (+bias).
// NT<=4: ping-pong double-buffered staging (T3-minimum 2-phase): issue
// stage(ks+1) BEFORE computing ks; ONE barrier per iter (its vmcnt(0) drain
// lands after ds_read+MFMA ran, so HBM latency overlaps compute).
// LDS 40 KB at NT=4 — occupancy unchanged (wave-capped at 4 blocks/CU).
// NT=8: single-buffer (Bs too large to double).
template<int NT>
__global__ __launch_bounds__(512, NT == 8 ? 2 : 4) void k_gemm_nres(
    const ushort_t* __restrict__ A, int lda,
    const ushort_t* __restrict__ B, int ldb,
    void* __restrict__ Cp, int ldc,
    const float* __restrict__ bias,
    int ksteps, int nlim, int bf16out)
{
    constexpr bool DB = (NT <= 4);
    constexpr int NROWS = NT * 64;                    // B rows resident
    constexpr int ASZ = 64 * 32;                      // As elems per buffer
    constexpr int BSZ = NROWS * 32;                   // Bs elems per buffer
    __shared__ __align__(16) ushort_t As[(DB ? 2 : 1) * ASZ];
    __shared__ __align__(16) ushort_t Bs[(DB ? 2 : 1) * BSZ];
    const int tid = threadIdx.x, lane = tid & 63, wave = tid >> 6;
    const int wm = wave >> 2, wn = wave & 3;
    const int R0 = (int)blockIdx.x * 64;

    const int ar = tid >> 2, acb = tid & 3;
    const bool aon = tid < 256;
    const int acl = acb ^ ((ar >> 1) & 3);
    const ushort_t* gA = A + (size_t)(R0 + ar) * lda + acl * 8;

    const int q = lane >> 4, fr = lane & 15;

    f32x4 acc[2][NT] = {};

    if constexpr (DB) {
        // stage helper: loads A,B k-slice ks into buffer p
        auto stage = [&](int ks, int p) {
            const int k0 = ks * 32;
            if (aon) async_copy16(gA + k0, &As[p * ASZ + tid * 8]);
#pragma unroll
            for (int it = 0; it < NT / 2; ++it) {
                const int ci  = it * 512 + tid;
                const int rb  = ci >> 2, cb2 = ci & 3;
                const int clb = cb2 ^ ((rb >> 1) & 3);
                async_copy16(B + (size_t)rb * ldb + k0 + clb * 8,
                             &Bs[p * BSZ + ci * 8]);
            }
        };
        stage(0, 0);
        __syncthreads();           // drain buf0
        int p = 0;
        for (int ks = 0; ks < ksteps; ++ks) {
            if (ks + 1 < ksteps) stage(ks + 1, p ^ 1);   // async, overlaps MFMA
            short8 a[2];
#pragma unroll
            for (int ms = 0; ms < 2; ++ms) {
                const int row = wm * 32 + ms * 16 + fr;
                a[ms] = *(const short8*)&As[p * ASZ +
                        (row * 4 + (q ^ ((row >> 1) & 3))) * 8];
            }
#pragma unroll
            for (int nt = 0; nt < NT; ++nt) {
                const int n = wn * (NT * 16) + nt * 16 + fr;
                const short8 b = *(const short8*)&Bs[p * BSZ +
                        (n * 4 + (q ^ ((n >> 1) & 3))) * 8];
#pragma unroll
                for (int ms = 0; ms < 2; ++ms)
                    acc[ms][nt] = __builtin_amdgcn_mfma_f32_16x16x32_bf16(
                        a[ms], b, acc[ms][nt], 0, 0, 0);
            }
            __syncthreads();       // drains stage(ks+1); guards buf reuse
            p ^= 1;
        }
    } else {
        for (int ks = 0; ks < ksteps; ++ks) {
            const int k0 = ks * 32;
            if (aon) async_copy16(gA + k0, &As[tid * 8]);
#pragma unroll
            for (int it = 0; it < NT / 2; ++it) {
                const int ci  = it * 512 + tid;
                const int rb  = ci >> 2, cb2 = ci & 3;
                const int clb = cb2 ^ ((rb >> 1) & 3);
                async_copy16(B + (size_t)rb * ldb + k0 + clb * 8, &Bs[ci * 8]);
            }
            __syncthreads();
            short8 a[2];
#pragma unroll
            for (int ms = 0; ms < 2; ++ms) {
                const int row = wm * 32 + ms * 16 + fr;
                a[ms] = *(const short8*)&As[(row * 4 + (q ^ ((row >> 1) & 3))) * 8];
            }
#pragma unroll
            for (int nt = 0; nt < NT; ++nt) {
                const int n = wn * (NT * 16) + nt * 16 + fr;
                const short8 b = *(const short8*)&Bs[(n * 4 + (q ^ ((n >> 1) & 3))) * 8];
#pragma unroll
                for (int ms = 0; ms < 2; ++ms)
                    acc[ms][nt] = __builtin_amdgcn_mfma_f32_16x16x32_bf16(
                        a[ms], b, acc[ms][nt], 0, 0, 0);
            }
            __syncthreads();
        }
    }

#pragma unroll
    for (int ms = 0; ms < 2; ++ms)
#pragma unroll
        for (int nt = 0; nt < NT; ++nt) {
            const int col = wn * (NT * 16) + nt * 16 + fr;
            if (col >= nlim) continue;
            const float bv = bias ? bias[col] : 0.f;
#pragma unroll
            for (int reg = 0; reg < 4; ++reg) {
                const int row = R0 + wm * 32 + ms * 16 + q * 4 + reg;
                const float v = acc[ms][nt][reg] + bv;
                if (bf16out) ((ushort_t*)Cp)[(size_t)row * ldc + col] = f2bf(v);
                else         ((float*)Cp)[(size_t)row * ldc + col] = v;
            }
        }
}

// LN(relu(Epre + enc_b)) -> Abuf cols [0,250). One wave per row, us4 loads.
__global__ __launch_bounds__(256) void k_lnenc(const ushort_t* __restrict__ Epre,
    const float* __restrict__ eb, const float* __restrict__ eg,
    const float* __restrict__ ebt, ushort_t* __restrict__ Abuf)
{
    const int wave = threadIdx.x >> 6, lane = threadIdx.x & 63;
    const int row = blockIdx.x * 4 + wave;
    const int c0 = 4 * lane;

    const us4 v = *(const us4*)&Epre[(size_t)row * 256 + c0];
    float y[4]; float sm = 0.f, sq = 0.f;
#pragma unroll
    for (int t = 0; t < 4; ++t) {
        const int cc = c0 + t;
        float z = 0.f;
        if (cc < H) z = fmaxf(bf2f(v[t]) + eb[cc], 0.f);
        y[t] = z; sm += z; sq += z * z;
    }
    sm = wave_sum_dpp(sm);
    sq = wave_sum_dpp(sq);
    const float mu = sm * (1.f / H);
    const float rs = __builtin_amdgcn_rsqf(sq * (1.f / H) - mu * mu + EPS);
    ushort_t o[4];
#pragma unroll
    for (int t = 0; t < 4; ++t) {
        const int cc = c0 + t;
        o[t] = (cc < H) ? f2bf((y[t] - mu) * rs * eg[cc] + ebt[cc]) : (ushort_t)0;
    }
    ushort_t* dst = Abuf + (size_t)row * KP + c0;
    if (c0 + 3 < H) { *(us4*)dst = (us4){o[0], o[1], o[2], o[3]}; }
    else {
        if (c0 + 1 < H) *(us2*)dst = (us2){o[0], o[1]};
    }
}

// Co[r][0:256] = LN(relu(P_g + Q_qr + core_b)) bf16. One wave per GROUP.
__global__ __launch_bounds__(256) void k_core(const ushort_t* __restrict__ PQb,
    const float* __restrict__ core_b, const float* __restrict__ core_g,
    const float* __restrict__ core_bt, ushort_t* __restrict__ Co)
{
    const int wave = threadIdx.x >> 6, lane = threadIdx.x & 63;
    const int g = blockIdx.x * 4 + wave;        // group 0..16383
    const int i = g & 7;
    const int c = lane * 4;

    const us4 pu = *(const us4*)&PQb[(size_t)g * PQS + c];
    us4 qu[7];
#pragma unroll
    for (int jj = 0; jj < 7; ++jj) {
        const int j = jj + (jj >= i ? 1 : 0);
        const int qr = (g & ~7) + j;
        qu[jj] = *(const us4*)&PQb[(size_t)qr * PQS + 256 + c];
    }
    float pe[4], cb[4], cg[4], cbt[4]; bool vl[4];
#pragma unroll
    for (int t = 0; t < 4; ++t) {
        vl[t]  = (c + t) < H;
        pe[t]  = bf2f(pu[t]);
        cb[t]  = vl[t] ? core_b[c + t]  : 0.f;
        cg[t]  = vl[t] ? core_g[c + t]  : 0.f;
        cbt[t] = vl[t] ? core_bt[c + t] : 0.f;
    }
    float z[7][4], red[7][2];
#pragma unroll
    for (int jj = 0; jj < 7; ++jj) {
        float sm = 0.f, sq = 0.f;
#pragma unroll
        for (int t = 0; t < 4; ++t) {
            const float zz = vl[t] ? fmaxf(pe[t] + bf2f(qu[jj][t]) + cb[t], 0.f) : 0.f;
            z[jj][t] = zz; sm += zz; sq = fmaf(zz, zz, sq);
        }
        red[jj][0] = sm; red[jj][1] = sq;
    }
#pragma unroll
    for (int jj = 0; jj < 7; ++jj) {
        red[jj][0] = wave_sum_dpp(red[jj][0]);
        red[jj][1] = wave_sum_dpp(red[jj][1]);
    }
#pragma unroll
    for (int jj = 0; jj < 7; ++jj) {
        const float mu = red[jj][0] * (1.f / H);
        const float rs = __builtin_amdgcn_rsqf(red[jj][1] * (1.f / H) - mu * mu + EPS);
        us4 o;
#pragma unroll
        for (int t = 0; t < 4; ++t)
            o[t] = vl[t] ? f2bf((z[jj][t] - mu) * rs * cg[t] + cbt[t]) : (ushort_t)0;
        *(us4*)&Co[((size_t)g * 7 + jj) * 256 + c] = o;
    }
}

// ================= k_cs: ping-pong GEMM + register-only stats epilogue =====
// GEMM = r8 k_cs with T3-minimum 2-phase staging (As+Bs ping-pong, one
// barrier/iter). LDS 56 KB -> 2 blocks/CU (was 4): trade vs hiding the
// 8x ~900cyc HBM drain of Co staging. Revert-signal: dur > 70 us.
// Epilogue (regs + bfly16 only): z -> Cs[row][256], partial stats -> Srow.
__global__ __launch_bounds__(512, 4) void k_cs(
    const ushort_t* __restrict__ Co,
    const ushort_t* __restrict__ Wca,   // [384][256] bf16
    const float* __restrict__ ctx_b,
    const float* __restrict__ att_b1, const float* __restrict__ att_g,
    const float* __restrict__ attW2,
    ushort_t* __restrict__ Cs, float* __restrict__ Srow)
{
    constexpr int ASZ = 64 * 32;      // 2048 elems = 4 KB
    constexpr int BSZ = 384 * 32;     // 12288 elems = 24 KB
    __shared__ __align__(16) ushort_t As[2 * ASZ];
    __shared__ __align__(16) ushort_t Bs[2 * BSZ];
    const int tid = threadIdx.x, lane = tid & 63, wave = tid >> 6;
    const int wmm = wave >> 2, wnn = wave & 3;
    const int R0 = (int)blockIdx.x * 64;

    const int ar = tid >> 2, acb = tid & 3;
    const bool aon = tid < 256;
    const int acl = acb ^ ((ar >> 1) & 3);
    const ushort_t* gA = Co + (size_t)(R0 + ar) * 256 + acl * 8;

    const int q = lane >> 4, fr = lane & 15;

    auto stage = [&](int ks, int p) {
        const int k0 = ks * 32;
        if (aon) async_copy16(gA + k0, &As[p * ASZ + tid * 8]);
#pragma unroll
        for (int it = 0; it < 3; ++it) {
            const int ci  = it * 512 + tid;
            const int rb  = ci >> 2, cb2 = ci & 3;
            const int clb = cb2 ^ ((rb >> 1) & 3);
            async_copy16(Wca + (size_t)rb * 256 + k0 + clb * 8,
                         &Bs[p * BSZ + ci * 8]);
        }
    };

    f32x4 acc[2][6] = {};
    stage(0, 0);
    __syncthreads();
    int p = 0;
    for (int ks = 0; ks < 8; ++ks) {
        if (ks + 1 < 8) stage(ks + 1, p ^ 1);   // async, overlaps MFMA
        short8 a[2];
#pragma unroll
        for (int ms = 0; ms < 2; ++ms) {
            const int row = wmm * 32 + ms * 16 + fr;
            a[ms] = *(const short8*)&As[p * ASZ +
                    (row * 4 + (q ^ ((row >> 1) & 3))) * 8];
        }
#pragma unroll
        for (int nt = 0; nt < 6; ++nt) {
            const int n = wnn * 96 + nt * 16 + fr;
            const short8 b = *(const short8*)&Bs[p * BSZ +
                    (n * 4 + (q ^ ((n >> 1) & 3))) * 8];
#pragma unroll
            for (int ms = 0; ms < 2; ++ms)
                acc[ms][nt] = __builtin_amdgcn_mfma_f32_16x16x32_bf16(
                    a[ms], b, acc[ms][nt], 0, 0, 0);
        }
        __syncthreads();           // drains stage(ks+1); guards buf reuse
        p ^= 1;
    }

    // ---- epilogue: per-col consts (loaded now; keeps GEMM regs unchanged) ----
    bool eC[6], eA[6]; float b_[6], gw[6];
#pragma unroll
    for (int nt = 0; nt < 6; ++nt) {
        const int col = wnn * 96 + nt * 16 + fr;
        eC[nt] = col < H;
        eA[nt] = (col >= H) && (col < H + HA);
        if (eC[nt])      { b_[nt] = ctx_b[col];      gw[nt] = 0.f; }
        else if (eA[nt]) { const int ca = col - H;
                           b_[nt] = att_b1[ca];
                           gw[nt] = att_g[ca] * attW2[ca]; }
        else             { b_[nt] = gw[nt] = 0.f; }
    }

    // per-ms pass bounds live registers (r8-proven transform)
#pragma unroll
    for (int ms = 0; ms < 2; ++ms) {
        float smc[4] = {}, sqc[4] = {}, sma[4] = {}, sqa[4] = {}, szgw[4] = {};
#pragma unroll
        for (int nt = 0; nt < 6; ++nt) {
#pragma unroll
            for (int reg = 0; reg < 4; ++reg) {
                const float val = acc[ms][nt][reg] + b_[nt];
                if (eC[nt]) {
                    const float zz = fmaxf(val, 0.f);
                    acc[ms][nt][reg] = zz;
                    smc[reg] += zz; sqc[reg] = fmaf(zz, zz, sqc[reg]);
                } else if (eA[nt]) {
                    const float za = ftanh(val);
                    sma[reg] += za; sqa[reg] = fmaf(za, za, sqa[reg]);
                    szgw[reg] = fmaf(za, gw[nt], szgw[reg]);
                }
            }
        }
#pragma unroll
        for (int reg = 0; reg < 4; ++reg) {
            smc[reg]  = bfly16_sum(smc[reg]);
            sqc[reg]  = bfly16_sum(sqc[reg]);
            sma[reg]  = bfly16_sum(sma[reg]);
            sqa[reg]  = bfly16_sum(sqa[reg]);
            szgw[reg] = bfly16_sum(szgw[reg]);
        }
        if (fr == 0) {
#pragma unroll
            for (int reg = 0; reg < 4; ++reg) {
                const int row = R0 + wmm * 32 + ms * 16 + q * 4 + reg;
                *(f32x4*)&Srow[(size_t)row * 32 + wnn * 8] =
                    (f32x4){smc[reg], sqc[reg], sma[reg], sqa[reg]};
                Srow[(size_t)row * 32 + wnn * 8 + 4] = szgw[reg];
            }
        }
        // write z (relu'd ctx) to Cs cols [0,256); att cols 250..255 get 0
#pragma unroll
        for (int nt = 0; nt < 6; ++nt) {
            const int col = wnn * 96 + nt * 16 + fr;
            if (col >= 256) continue;
#pragma unroll
            for (int reg = 0; reg < 4; ++reg) {
                const int row = R0 + wmm * 32 + ms * 16 + q * 4 + reg;
                Cs[(size_t)row * 256 + col] =
                    eC[nt] ? f2bf(acc[ms][nt][reg]) : (ushort_t)0;
            }
        }
    }
}

// ================= k_eff2: fold partials + gate + weighted sum =================
// One wave per group. Pure streaming: reads 7x256 z (bf16) + 7x20 scalars.
__global__ __launch_bounds__(256) void k_eff2(
    const ushort_t* __restrict__ Cs, const float* __restrict__ Srow,
    const float* __restrict__ ctx_g, const float* __restrict__ ctx_bt,
    const float* __restrict__ att_g, const float* __restrict__ att_bt,
    const float* __restrict__ attW2, const float* __restrict__ att_b2,
    ushort_t* __restrict__ Abuf)
{
    const int wave = threadIdx.x >> 6, lane = threadIdx.x & 63;
    const int g = blockIdx.x * 4 + wave;
    const int c0 = 4 * lane;

    // row-invariant attention sums
    float psg = 0.f, psb = 0.f;
    for (int c = lane; c < HA; c += 64) {
        const float w2 = attW2[c];
        psg = fmaf(att_g[c], w2, psg);
        psb = fmaf(att_bt[c], w2, psb);
    }
    psg = wave_sum_dpp(psg); psb = wave_sum_dpp(psb);
    const float sgw = psg;
    const float ab2 = att_b2[0] + psb;

    float g4[4], bt4[4];
#pragma unroll
    for (int t = 0; t < 4; ++t) {
        const bool vl = (c0 + t) < H;
        g4[t]  = vl ? ctx_g[c0 + t]  : 0.f;
        bt4[t] = vl ? ctx_bt[c0 + t] : 0.f;
    }

    // prefetch z rows
    us4 zv[7];
#pragma unroll
    for (int jj = 0; jj < 7; ++jj)
        zv[jj] = *(const us4*)&Cs[((size_t)g * 7 + jj) * 256 + c0];

    float A4[4] = {0.f, 0.f, 0.f, 0.f};
    float S0 = 0.f, S1 = 0.f;
#pragma unroll
    for (int jj = 0; jj < 7; ++jj) {
        const float* sr = Srow + ((size_t)g * 7 + jj) * 32;
        float s0 = 0.f, s1 = 0.f, s2 = 0.f, s3 = 0.f, s4 = 0.f;
#pragma unroll
        for (int w = 0; w < 4; ++w) {
            const f32x4 v = *(const f32x4*)&sr[w * 8];
            s0 += v[0]; s1 += v[1]; s2 += v[2]; s3 += v[3];
            s4 += sr[w * 8 + 4];
        }
        const float muC = s0 * (1.f / H);
        const float rsC = __builtin_amdgcn_rsqf(s1 * (1.f / H) - muC * muC + EPS);
        const float muA = s2 * (1.f / HA);
        const float rsA = __builtin_amdgcn_rsqf(s3 * (1.f / HA) - muA * muA + EPS);
        const float dot = rsA * (s4 - muA * sgw) + ab2;
        const float ag  = fsigmoid(dot);
        const float cj  = ag * rsC;
        S0 += ag; S1 = fmaf(cj, muC, S1);
#pragma unroll
        for (int e = 0; e < 4; ++e)
            A4[e] = fmaf(cj, bf2f(zv[jj][e]), A4[e]);
    }
    ushort_t o[4];
#pragma unroll
    for (int e = 0; e < 4; ++e)
        o[e] = f2bf(g4[e] * (A4[e] - S1) + bt4[e] * S0);
    ushort_t* dst = Abuf + (size_t)g * KP + H + c0;
    if (c0 + 1 < H) *(us2*)dst       = (us2){o[0], o[1]};
    if (c0 + 3 < H) *(us2*)(dst + 2) = (us2){o[2], o[3]};
}

extern "C" void kernel_launch(void* const* d_in, const int* in_sizes, int n_in,
                              void* d_out, int out_size, void* d_ws, size_t ws_size,
                              hipStream_t stream)
{
    const float* x      = (const float*)d_in[0];
    const float* state  = (const float*)d_in[1];
    const float* enc_W  = (const float*)d_in[2];
    const float* enc_b  = (const float*)d_in[3];
    const float* enc_g  = (const float*)d_in[4];
    const float* enc_bt = (const float*)d_in[5];
    const float* core_W = (const float*)d_in[6];
    const float* core_b = (const float*)d_in[7];
    const float* core_g = (const float*)d_in[8];
    const float* core_bt= (const float*)d_in[9];
    const float* ctx_W  = (const float*)d_in[10];
    const float* ctx_b  = (const float*)d_in[11];
    const float* ctx_g  = (const float*)d_in[12];
    const float* ctx_bt = (const float*)d_in[13];
    const float* att_W1 = (const float*)d_in[14];
    const float* att_b1 = (const float*)d_in[15];
    const float* att_g  = (const float*)d_in[16];
    const float* att_bt = (const float*)d_in[17];
    const float* att_W2 = (const float*)d_in[18];
    const float* att_b2 = (const float*)d_in[19];
    const float* out_W  = (const float*)d_in[20];
    const float* out_b  = (const float*)d_in[21];
    float* out = (float*)d_out;

    // layout (ushort units); Sb/Epre/PQb alias the Cs region (dead before k_cs)
    ushort_t* Abuf = (ushort_t*)d_ws;                   // 16384*1088      (35.7 MB)
    ushort_t* Wt   = Abuf + (size_t)ROWS * KP;          // 256*1088
    ushort_t* Wpq  = Wt + (size_t)256 * KP;             // 512*256
    ushort_t* Wca  = Wpq + (size_t)512 * 256;           // 384*256
    ushort_t* Wenc = Wca + (size_t)384 * 256;           // 256*256
    ushort_t* Co   = Wenc + (size_t)256 * 256;          // 114688*256     (58.7 MB)
    ushort_t* Cs   = Co + (size_t)PROWS * 256;          // 114688*256     (58.7 MB)
    float*    Srow = (float*)(Cs + (size_t)PROWS * 256);// 114688*32 f32  (14.7 MB)
    ushort_t* Sb   = Cs;                                // 16384*256  (aliased)
    ushort_t* Epre = Sb + (size_t)ROWS * 256;           // 16384*256  (aliased)
    ushort_t* PQb  = Epre + (size_t)ROWS * 256;         // 16384*512  (aliased)

    k_prep  <<<3456, 256, 0, stream>>>(out_W, core_W, ctx_W, att_W1, enc_W,
                                       state, x, Wt, Wpq, Wca, Wenc, Sb, Abuf);
    // Epre = state @ enc_W  (bf16 MFMA, N=256 resident, ping-pong)
    k_gemm_nres<4><<<ROWS / 64, 512, 0, stream>>>(Sb, 256, Wenc, 256, Epre, 256,
                                                  nullptr, 8, 256, 1);
    k_lnenc <<<ROWS / 4, 256, 0, stream>>>(Epre, enc_b, enc_g, enc_bt, Abuf);
    // PQb = s1 @ [W_top | W_bot]  (bf16 MFMA, N=512 resident, bf16 out)
    k_gemm_nres<8><<<ROWS / 64, 512, 0, stream>>>(Abuf, KP, Wpq, 256, PQb, PQS,
                                                  nullptr, 8, 512, 1);
    k_core  <<<ROWS / 4, 256, 0, stream>>>(PQb, core_b, core_g, core_bt, Co);
    // ping-pong GEMM + stats epilogue (z -> Cs, partial stats -> Srow)
    k_cs    <<<PROWS / 64, 512, 0, stream>>>(Co, Wca, ctx_b, att_b1, att_g,
                                             att_W2, Cs, Srow);
    // fold partials + gate + weighted sum -> eff
    k_eff2  <<<ROWS / 4, 256, 0, stream>>>(Cs, Srow, ctx_g, ctx_bt,
                                           att_g, att_bt, att_W2, att_b2, Abuf);
    // out = [s1 | eff | x] @ out_W + b  (bf16 MFMA, N=256 resident, ping-pong)
    k_gemm_nres<4><<<ROWS / 64, 512, 0, stream>>>(Abuf, KP, Wt, KP, out, H,
                                                  out_b, KP / 32, 250, 0);
}

// Round 11
// 335.599 us; speedup vs baseline: 1.3342x; 1.0055x over previous
//
#include <hip/hip_runtime.h>
#include <math.h>

#define KK 8
#define H 250          // SIZE == h1
#define MDIM 576
#define NB 2048
#define HA 100
#define ROWS (NB*KK)   // 16384
#define PROWS (ROWS*7) // 114688 pair rows
#define PQS 512        // PQb row stride (ushort): P at 0..249, Q at 256..505
#define KP 1088        // padded K for out GEMM (1076 -> 34*32)
#define EPS 1e-5f

typedef unsigned short ushort_t;
typedef short short8 __attribute__((ext_vector_type(8)));
typedef unsigned short us8 __attribute__((ext_vector_type(8)));
typedef unsigned short us4 __attribute__((ext_vector_type(4)));
typedef unsigned short us2 __attribute__((ext_vector_type(2)));
typedef float f32x4 __attribute__((ext_vector_type(4)));

// ---- DPP helpers (old=0 + bound_ctrl=1 so GCNDPPCombine folds to v_add_f32_dpp) ----
template<int CTRL>
__device__ __forceinline__ float dpp_add_f32(float x) {
    const int s = __builtin_amdgcn_update_dpp(
        0, __builtin_bit_cast(int, x), CTRL, 0xF, 0xF, true);
    return x + __builtin_bit_cast(float, s);
}
// full-wave (64-lane) sum; result broadcast wave-uniform via readlane(63)
__device__ __forceinline__ float wave_sum_dpp(float x) {
    x = dpp_add_f32<0x111>(x);  // row_shr:1
    x = dpp_add_f32<0x112>(x);  // row_shr:2
    x = dpp_add_f32<0x114>(x);  // row_shr:4
    x = dpp_add_f32<0x118>(x);  // row_shr:8
    x = dpp_add_f32<0x142>(x);  // row_bcast:15
    x = dpp_add_f32<0x143>(x);  // row_bcast:31 -> lane 63 holds total
    return __builtin_bit_cast(float, __builtin_amdgcn_readlane(
        __builtin_bit_cast(int, x), 63));
}
// 16-lane butterfly sum: result present in ALL 16 lanes of each 16-lane row
__device__ __forceinline__ float bfly16_sum(float x) {
    x = dpp_add_f32<0xB1>(x);   // quad_perm [1,0,3,2]  (xor 1)
    x = dpp_add_f32<0x4E>(x);   // quad_perm [2,3,0,1]  (xor 2)
    x = dpp_add_f32<0x141>(x);  // row_half_mirror      (pairs across quads)
    x = dpp_add_f32<0x140>(x);  // row_mirror           (pairs across halves)
    return x;
}

__device__ __forceinline__ void async_copy16(const void* g, void* l) {
    __builtin_amdgcn_global_load_lds(
        (const __attribute__((address_space(1))) void*)g,
        (__attribute__((address_space(3))) void*)l, 16, 0, 0);
}

__device__ __forceinline__ ushort_t f2bf(float v) {
    union { float f; unsigned int u; } c; c.f = v;
    unsigned int x = c.u;
    x += 0x7fff + ((x >> 16) & 1);   // RNE
    return (ushort_t)(x >> 16);
}
__device__ __forceinline__ float bf2f(ushort_t v) {
    union { unsigned int u; float f; } c; c.u = ((unsigned int)v) << 16;
    return c.f;
}
// fast tanh: 1 - 2/(exp(2x)+1)  (v_exp + v_rcp; ~1e-6 rel err, << bf16 ulp)
__device__ __forceinline__ float ftanh(float x) {
    const float e = __expf(2.f * x);
    return 1.f - 2.f * __builtin_amdgcn_rcpf(e + 1.f);
}
__device__ __forceinline__ float fsigmoid(float x) {
    return __builtin_amdgcn_rcpf(1.f + __expf(-x));
}

// ---- fused prep: Wt | Wpq | Wca | Wenc | Sb | x->Abuf (16 rows/block) ----
__global__ __launch_bounds__(256) void k_prep(
    const float* __restrict__ out_W, const float* __restrict__ core_W,
    const float* __restrict__ ctx_W, const float* __restrict__ att_W1,
    const float* __restrict__ enc_W, const float* __restrict__ state,
    const float* __restrict__ x,
    ushort_t* __restrict__ Wt, ushort_t* __restrict__ Wpq,
    ushort_t* __restrict__ Wca, ushort_t* __restrict__ Wenc,
    ushort_t* __restrict__ Sb, ushort_t* __restrict__ Abuf)
{
    const int b = blockIdx.x, t = threadIdx.x;
    if (b < 256) {                      // Wt[n][k] = out_W[k][n]
        const int n = b;
        for (int k = t; k < KP; k += 256) {
            const float v = (n < H && k < 1076) ? out_W[(size_t)k * H + n] : 0.f;
            Wt[(size_t)n * KP + k] = f2bf(v);
        }
    } else if (b < 768) {               // Wpq
        const int n = b - 256, k = t;
        float v = 0.f;
        if (k < H) {
            if (n < H)                    v = core_W[(size_t)k * H + n];
            else if (n >= 256 && n < 506) v = core_W[(size_t)(H + k) * H + (n - 256)];
        }
        Wpq[(size_t)n * 256 + k] = f2bf(v);
    } else if (b < 1152) {              // Wca
        const int n = b - 768, k = t;
        float v = 0.f;
        if (k < H) {
            if (n < H)           v = ctx_W[(size_t)k * H + n];
            else if (n < H + HA) v = att_W1[(size_t)k * HA + (n - H)];
        }
        Wca[(size_t)n * 256 + k] = f2bf(v);
    } else if (b < 1408) {              // Wenc[n][k] = enc_W[k][n]
        const int n = b - 1152, k = t;
        const float v = (n < H && k < H) ? enc_W[(size_t)k * H + n] : 0.f;
        Wenc[(size_t)n * 256 + k] = f2bf(v);
    } else if (b < 2432) {              // Sb: state padded to 256, bf16
        const int r0 = (b - 1408) * 16;
        for (int idx = t; idx < 16 * 256; idx += 256) {
            const int r = r0 + (idx >> 8), k = idx & 255;
            const float v = (k < H) ? state[(size_t)r * H + k] : 0.f;
            Sb[(size_t)r * 256 + k] = f2bf(v);
        }
    } else {                            // Abuf cols [500,1088): x + pad, 16 rows/block
        const int r0 = (b - 2432) * 16;
        for (int idx = t; idx < 16 * 588; idx += 256) {
            const int r = r0 + idx / 588, c = 500 + idx % 588;
            const float v = (c < 500 + MDIM) ? x[(size_t)r * MDIM + (c - 500)] : 0.f;
            Abuf[(size_t)r * KP + c] = f2bf(v);
        }
    }
}

// N-resident bf16 MFMA GEMM: C[m][n] = sum_k A[m][k]*B[n][k] (+bias).
// NT<=4: ping-pong double-buffered staging (kept from r10 — LDS 40 KB is
// FREE at the 4-block/CU wave-cap, and r10 showed ~25 us combined gain).
// NT=8: single-buffer (Bs too large to double).
template<int NT>
__global__ __launch_bounds__(512, NT == 8 ? 2 : 4) void k_gemm_nres(
    const ushort_t* __restrict__ A, int lda,
    const ushort_t* __restrict__ B, int ldb,
    void* __restrict__ Cp, int ldc,
    const float* __restrict__ bias,
    int ksteps, int nlim, int bf16out)
{
    constexpr bool DB = (NT <= 4);
    constexpr int NROWS = NT * 64;                    // B rows resident
    constexpr int ASZ = 64 * 32;                      // As elems per buffer
    constexpr int BSZ = NROWS * 32;                   // Bs elems per buffer
    __shared__ __align__(16) ushort_t As[(DB ? 2 : 1) * ASZ];
    __shared__ __align__(16) ushort_t Bs[(DB ? 2 : 1) * BSZ];
    const int tid = threadIdx.x, lane = tid & 63, wave = tid >> 6;
    const int wm = wave >> 2, wn = wave & 3;
    const int R0 = (int)blockIdx.x * 64;

    const int ar = tid >> 2, acb = tid & 3;
    const bool aon = tid < 256;
    const int acl = acb ^ ((ar >> 1) & 3);
    const ushort_t* gA = A + (size_t)(R0 + ar) * lda + acl * 8;

    const int q = lane >> 4, fr = lane & 15;

    f32x4 acc[2][NT] = {};

    if constexpr (DB) {
        // stage helper: loads A,B k-slice ks into buffer p
        auto stage = [&](int ks, int p) {
            const int k0 = ks * 32;
            if (aon) async_copy16(gA + k0, &As[p * ASZ + tid * 8]);
#pragma unroll
            for (int it = 0; it < NT / 2; ++it) {
                const int ci  = it * 512 + tid;
                const int rb  = ci >> 2, cb2 = ci & 3;
                const int clb = cb2 ^ ((rb >> 1) & 3);
                async_copy16(B + (size_t)rb * ldb + k0 + clb * 8,
                             &Bs[p * BSZ + ci * 8]);
            }
        };
        stage(0, 0);
        __syncthreads();           // drain buf0
        int p = 0;
        for (int ks = 0; ks < ksteps; ++ks) {
            if (ks + 1 < ksteps) stage(ks + 1, p ^ 1);   // async, overlaps MFMA
            short8 a[2];
#pragma unroll
            for (int ms = 0; ms < 2; ++ms) {
                const int row = wm * 32 + ms * 16 + fr;
                a[ms] = *(const short8*)&As[p * ASZ +
                        (row * 4 + (q ^ ((row >> 1) & 3))) * 8];
            }
#pragma unroll
            for (int nt = 0; nt < NT; ++nt) {
                const int n = wn * (NT * 16) + nt * 16 + fr;
                const short8 b = *(const short8*)&Bs[p * BSZ +
                        (n * 4 + (q ^ ((n >> 1) & 3))) * 8];
#pragma unroll
                for (int ms = 0; ms < 2; ++ms)
                    acc[ms][nt] = __builtin_amdgcn_mfma_f32_16x16x32_bf16(
                        a[ms], b, acc[ms][nt], 0, 0, 0);
            }
            __syncthreads();       // drains stage(ks+1); guards buf reuse
            p ^= 1;
        }
    } else {
        for (int ks = 0; ks < ksteps; ++ks) {
            const int k0 = ks * 32;
            if (aon) async_copy16(gA + k0, &As[tid * 8]);
#pragma unroll
            for (int it = 0; it < NT / 2; ++it) {
                const int ci  = it * 512 + tid;
                const int rb  = ci >> 2, cb2 = ci & 3;
                const int clb = cb2 ^ ((rb >> 1) & 3);
                async_copy16(B + (size_t)rb * ldb + k0 + clb * 8, &Bs[ci * 8]);
            }
            __syncthreads();
            short8 a[2];
#pragma unroll
            for (int ms = 0; ms < 2; ++ms) {
                const int row = wm * 32 + ms * 16 + fr;
                a[ms] = *(const short8*)&As[(row * 4 + (q ^ ((row >> 1) & 3))) * 8];
            }
#pragma unroll
            for (int nt = 0; nt < NT; ++nt) {
                const int n = wn * (NT * 16) + nt * 16 + fr;
                const short8 b = *(const short8*)&Bs[(n * 4 + (q ^ ((n >> 1) & 3))) * 8];
#pragma unroll
                for (int ms = 0; ms < 2; ++ms)
                    acc[ms][nt] = __builtin_amdgcn_mfma_f32_16x16x32_bf16(
                        a[ms], b, acc[ms][nt], 0, 0, 0);
            }
            __syncthreads();
        }
    }

#pragma unroll
    for (int ms = 0; ms < 2; ++ms)
#pragma unroll
        for (int nt = 0; nt < NT; ++nt) {
            const int col = wn * (NT * 16) + nt * 16 + fr;
            if (col >= nlim) continue;
            const float bv = bias ? bias[col] : 0.f;
#pragma unroll
            for (int reg = 0; reg < 4; ++reg) {
                const int row = R0 + wm * 32 + ms * 16 + q * 4 + reg;
                const float v = acc[ms][nt][reg] + bv;
                if (bf16out) ((ushort_t*)Cp)[(size_t)row * ldc + col] = f2bf(v);
                else         ((float*)Cp)[(size_t)row * ldc + col] = v;
            }
        }
}

// LN(relu(Epre + enc_b)) -> Abuf cols [0,250). One wave per row, us4 loads.
__global__ __launch_bounds__(256) void k_lnenc(const ushort_t* __restrict__ Epre,
    const float* __restrict__ eb, const float* __restrict__ eg,
    const float* __restrict__ ebt, ushort_t* __restrict__ Abuf)
{
    const int wave = threadIdx.x >> 6, lane = threadIdx.x & 63;
    const int row = blockIdx.x * 4 + wave;
    const int c0 = 4 * lane;

    const us4 v = *(const us4*)&Epre[(size_t)row * 256 + c0];
    float y[4]; float sm = 0.f, sq = 0.f;
#pragma unroll
    for (int t = 0; t < 4; ++t) {
        const int cc = c0 + t;
        float z = 0.f;
        if (cc < H) z = fmaxf(bf2f(v[t]) + eb[cc], 0.f);
        y[t] = z; sm += z; sq += z * z;
    }
    sm = wave_sum_dpp(sm);
    sq = wave_sum_dpp(sq);
    const float mu = sm * (1.f / H);
    const float rs = __builtin_amdgcn_rsqf(sq * (1.f / H) - mu * mu + EPS);
    ushort_t o[4];
#pragma unroll
    for (int t = 0; t < 4; ++t) {
        const int cc = c0 + t;
        o[t] = (cc < H) ? f2bf((y[t] - mu) * rs * eg[cc] + ebt[cc]) : (ushort_t)0;
    }
    ushort_t* dst = Abuf + (size_t)row * KP + c0;
    if (c0 + 3 < H) { *(us4*)dst = (us4){o[0], o[1], o[2], o[3]}; }
    else {
        if (c0 + 1 < H) *(us2*)dst = (us2){o[0], o[1]};
    }
}

// Co[r][0:256] = LN(relu(P_g + Q_qr + core_b)) bf16. One wave per GROUP.
__global__ __launch_bounds__(256) void k_core(const ushort_t* __restrict__ PQb,
    const float* __restrict__ core_b, const float* __restrict__ core_g,
    const float* __restrict__ core_bt, ushort_t* __restrict__ Co)
{
    const int wave = threadIdx.x >> 6, lane = threadIdx.x & 63;
    const int g = blockIdx.x * 4 + wave;        // group 0..16383
    const int i = g & 7;
    const int c = lane * 4;

    const us4 pu = *(const us4*)&PQb[(size_t)g * PQS + c];
    us4 qu[7];
#pragma unroll
    for (int jj = 0; jj < 7; ++jj) {
        const int j = jj + (jj >= i ? 1 : 0);
        const int qr = (g & ~7) + j;
        qu[jj] = *(const us4*)&PQb[(size_t)qr * PQS + 256 + c];
    }
    float pe[4], cb[4], cg[4], cbt[4]; bool vl[4];
#pragma unroll
    for (int t = 0; t < 4; ++t) {
        vl[t]  = (c + t) < H;
        pe[t]  = bf2f(pu[t]);
        cb[t]  = vl[t] ? core_b[c + t]  : 0.f;
        cg[t]  = vl[t] ? core_g[c + t]  : 0.f;
        cbt[t] = vl[t] ? core_bt[c + t] : 0.f;
    }
    float z[7][4], red[7][2];
#pragma unroll
    for (int jj = 0; jj < 7; ++jj) {
        float sm = 0.f, sq = 0.f;
#pragma unroll
        for (int t = 0; t < 4; ++t) {
            const float zz = vl[t] ? fmaxf(pe[t] + bf2f(qu[jj][t]) + cb[t], 0.f) : 0.f;
            z[jj][t] = zz; sm += zz; sq = fmaf(zz, zz, sq);
        }
        red[jj][0] = sm; red[jj][1] = sq;
    }
#pragma unroll
    for (int jj = 0; jj < 7; ++jj) {
        red[jj][0] = wave_sum_dpp(red[jj][0]);
        red[jj][1] = wave_sum_dpp(red[jj][1]);
    }
#pragma unroll
    for (int jj = 0; jj < 7; ++jj) {
        const float mu = red[jj][0] * (1.f / H);
        const float rs = __builtin_amdgcn_rsqf(red[jj][1] * (1.f / H) - mu * mu + EPS);
        us4 o;
#pragma unroll
        for (int t = 0; t < 4; ++t)
            o[t] = vl[t] ? f2bf((z[jj][t] - mu) * rs * cg[t] + cbt[t]) : (ushort_t)0;
        *(us4*)&Co[((size_t)g * 7 + jj) * 256 + c] = o;
    }
}

// ================= k_cs: single-buffer GEMM + register-only stats epilogue ==
// GEMM = r8 k_cs verbatim (LDS 28.6 KB, 4 blocks/CU). r10's ping-pong
// REGRESSED 63->86 us (LDS 57 KB halved residency) — occupancy beats
// intra-block pipelining for this latency-bound kernel. DO NOT add LDS.
// Epilogue (regs + bfly16 only): z -> Cs[row][256], partial stats -> Srow.
__global__ __launch_bounds__(512, 4) void k_cs(
    const ushort_t* __restrict__ Co,
    const ushort_t* __restrict__ Wca,   // [384][256] bf16
    const float* __restrict__ ctx_b,
    const float* __restrict__ att_b1, const float* __restrict__ att_g,
    const float* __restrict__ attW2,
    ushort_t* __restrict__ Cs, float* __restrict__ Srow)
{
    __shared__ __align__(16) ushort_t As[64 * 32];    // 4096 B
    __shared__ __align__(16) ushort_t Bs[384 * 32];   // 24576 B
    const int tid = threadIdx.x, lane = tid & 63, wave = tid >> 6;
    const int wmm = wave >> 2, wnn = wave & 3;
    const int R0 = (int)blockIdx.x * 64;

    const int ar = tid >> 2, acb = tid & 3;
    const bool aon = tid < 256;
    const int acl = acb ^ ((ar >> 1) & 3);
    const ushort_t* gA = Co + (size_t)(R0 + ar) * 256 + acl * 8;

    const int q = lane >> 4, fr = lane & 15;

    f32x4 acc[2][6] = {};
    for (int ks = 0; ks < 8; ++ks) {
        const int k0 = ks * 32;
        if (aon) async_copy16(gA + k0, &As[tid * 8]);
#pragma unroll
        for (int it = 0; it < 3; ++it) {
            const int ci  = it * 512 + tid;
            const int rb  = ci >> 2, cb2 = ci & 3;
            const int clb = cb2 ^ ((rb >> 1) & 3);
            async_copy16(Wca + (size_t)rb * 256 + k0 + clb * 8, &Bs[ci * 8]);
        }
        __syncthreads();
        short8 a[2];
#pragma unroll
        for (int ms = 0; ms < 2; ++ms) {
            const int row = wmm * 32 + ms * 16 + fr;
            a[ms] = *(const short8*)&As[(row * 4 + (q ^ ((row >> 1) & 3))) * 8];
        }
#pragma unroll
        for (int nt = 0; nt < 6; ++nt) {
            const int n = wnn * 96 + nt * 16 + fr;
            const short8 b = *(const short8*)&Bs[(n * 4 + (q ^ ((n >> 1) & 3))) * 8];
#pragma unroll
            for (int ms = 0; ms < 2; ++ms)
                acc[ms][nt] = __builtin_amdgcn_mfma_f32_16x16x32_bf16(
                    a[ms], b, acc[ms][nt], 0, 0, 0);
        }
        __syncthreads();
    }

    // ---- epilogue: per-col consts (loaded now; keeps GEMM regs unchanged) ----
    bool eC[6], eA[6]; float b_[6], gw[6];
#pragma unroll
    for (int nt = 0; nt < 6; ++nt) {
        const int col = wnn * 96 + nt * 16 + fr;
        eC[nt] = col < H;
        eA[nt] = (col >= H) && (col < H + HA);
        if (eC[nt])      { b_[nt] = ctx_b[col];      gw[nt] = 0.f; }
        else if (eA[nt]) { const int ca = col - H;
                           b_[nt] = att_b1[ca];
                           gw[nt] = att_g[ca] * attW2[ca]; }
        else             { b_[nt] = gw[nt] = 0.f; }
    }

    // per-ms pass bounds live registers (r8-proven transform)
#pragma unroll
    for (int ms = 0; ms < 2; ++ms) {
        float smc[4] = {}, sqc[4] = {}, sma[4] = {}, sqa[4] = {}, szgw[4] = {};
#pragma unroll
        for (int nt = 0; nt < 6; ++nt) {
#pragma unroll
            for (int reg = 0; reg < 4; ++reg) {
                const float val = acc[ms][nt][reg] + b_[nt];
                if (eC[nt]) {
                    const float zz = fmaxf(val, 0.f);
                    acc[ms][nt][reg] = zz;
                    smc[reg] += zz; sqc[reg] = fmaf(zz, zz, sqc[reg]);
                } else if (eA[nt]) {
                    const float za = ftanh(val);
                    sma[reg] += za; sqa[reg] = fmaf(za, za, sqa[reg]);
                    szgw[reg] = fmaf(za, gw[nt], szgw[reg]);
                }
            }
        }
#pragma unroll
        for (int reg = 0; reg < 4; ++reg) {
            smc[reg]  = bfly16_sum(smc[reg]);
            sqc[reg]  = bfly16_sum(sqc[reg]);
            sma[reg]  = bfly16_sum(sma[reg]);
            sqa[reg]  = bfly16_sum(sqa[reg]);
            szgw[reg] = bfly16_sum(szgw[reg]);
        }
        if (fr == 0) {
#pragma unroll
            for (int reg = 0; reg < 4; ++reg) {
                const int row = R0 + wmm * 32 + ms * 16 + q * 4 + reg;
                *(f32x4*)&Srow[(size_t)row * 32 + wnn * 8] =
                    (f32x4){smc[reg], sqc[reg], sma[reg], sqa[reg]};
                Srow[(size_t)row * 32 + wnn * 8 + 4] = szgw[reg];
            }
        }
        // write z (relu'd ctx) to Cs cols [0,256); att cols 250..255 get 0
#pragma unroll
        for (int nt = 0; nt < 6; ++nt) {
            const int col = wnn * 96 + nt * 16 + fr;
            if (col >= 256) continue;
#pragma unroll
            for (int reg = 0; reg < 4; ++reg) {
                const int row = R0 + wmm * 32 + ms * 16 + q * 4 + reg;
                Cs[(size_t)row * 256 + col] =
                    eC[nt] ? f2bf(acc[ms][nt][reg]) : (ushort_t)0;
            }
        }
    }
}

// ================= k_eff2: fold partials + gate + weighted sum =================
// One wave per group. Pure streaming: reads 7x256 z (bf16) + 7x20 scalars.
__global__ __launch_bounds__(256) void k_eff2(
    const ushort_t* __restrict__ Cs, const float* __restrict__ Srow,
    const float* __restrict__ ctx_g, const float* __restrict__ ctx_bt,
    const float* __restrict__ att_g, const float* __restrict__ att_bt,
    const float* __restrict__ attW2, const float* __restrict__ att_b2,
    ushort_t* __restrict__ Abuf)
{
    const int wave = threadIdx.x >> 6, lane = threadIdx.x & 63;
    const int g = blockIdx.x * 4 + wave;
    const int c0 = 4 * lane;

    // row-invariant attention sums
    float psg = 0.f, psb = 0.f;
    for (int c = lane; c < HA; c += 64) {
        const float w2 = attW2[c];
        psg = fmaf(att_g[c], w2, psg);
        psb = fmaf(att_bt[c], w2, psb);
    }
    psg = wave_sum_dpp(psg); psb = wave_sum_dpp(psb);
    const float sgw = psg;
    const float ab2 = att_b2[0] + psb;

    float g4[4], bt4[4];
#pragma unroll
    for (int t = 0; t < 4; ++t) {
        const bool vl = (c0 + t) < H;
        g4[t]  = vl ? ctx_g[c0 + t]  : 0.f;
        bt4[t] = vl ? ctx_bt[c0 + t] : 0.f;
    }

    // prefetch z rows
    us4 zv[7];
#pragma unroll
    for (int jj = 0; jj < 7; ++jj)
        zv[jj] = *(const us4*)&Cs[((size_t)g * 7 + jj) * 256 + c0];

    float A4[4] = {0.f, 0.f, 0.f, 0.f};
    float S0 = 0.f, S1 = 0.f;
#pragma unroll
    for (int jj = 0; jj < 7; ++jj) {
        const float* sr = Srow + ((size_t)g * 7 + jj) * 32;
        float s0 = 0.f, s1 = 0.f, s2 = 0.f, s3 = 0.f, s4 = 0.f;
#pragma unroll
        for (int w = 0; w < 4; ++w) {
            const f32x4 v = *(const f32x4*)&sr[w * 8];
            s0 += v[0]; s1 += v[1]; s2 += v[2]; s3 += v[3];
            s4 += sr[w * 8 + 4];
        }
        const float muC = s0 * (1.f / H);
        const float rsC = __builtin_amdgcn_rsqf(s1 * (1.f / H) - muC * muC + EPS);
        const float muA = s2 * (1.f / HA);
        const float rsA = __builtin_amdgcn_rsqf(s3 * (1.f / HA) - muA * muA + EPS);
        const float dot = rsA * (s4 - muA * sgw) + ab2;
        const float ag  = fsigmoid(dot);
        const float cj  = ag * rsC;
        S0 += ag; S1 = fmaf(cj, muC, S1);
#pragma unroll
        for (int e = 0; e < 4; ++e)
            A4[e] = fmaf(cj, bf2f(zv[jj][e]), A4[e]);
    }
    ushort_t o[4];
#pragma unroll
    for (int e = 0; e < 4; ++e)
        o[e] = f2bf(g4[e] * (A4[e] - S1) + bt4[e] * S0);
    ushort_t* dst = Abuf + (size_t)g * KP + H + c0;
    if (c0 + 1 < H) *(us2*)dst       = (us2){o[0], o[1]};
    if (c0 + 3 < H) *(us2*)(dst + 2) = (us2){o[2], o[3]};
}

extern "C" void kernel_launch(void* const* d_in, const int* in_sizes, int n_in,
                              void* d_out, int out_size, void* d_ws, size_t ws_size,
                              hipStream_t stream)
{
    const float* x      = (const float*)d_in[0];
    const float* state  = (const float*)d_in[1];
    const float* enc_W  = (const float*)d_in[2];
    const float* enc_b  = (const float*)d_in[3];
    const float* enc_g  = (const float*)d_in[4];
    const float* enc_bt = (const float*)d_in[5];
    const float* core_W = (const float*)d_in[6];
    const float* core_b = (const float*)d_in[7];
    const float* core_g = (const float*)d_in[8];
    const float* core_bt= (const float*)d_in[9];
    const float* ctx_W  = (const float*)d_in[10];
    const float* ctx_b  = (const float*)d_in[11];
    const float* ctx_g  = (const float*)d_in[12];
    const float* ctx_bt = (const float*)d_in[13];
    const float* att_W1 = (const float*)d_in[14];
    const float* att_b1 = (const float*)d_in[15];
    const float* att_g  = (const float*)d_in[16];
    const float* att_bt = (const float*)d_in[17];
    const float* att_W2 = (const float*)d_in[18];
    const float* att_b2 = (const float*)d_in[19];
    const float* out_W  = (const float*)d_in[20];
    const float* out_b  = (const float*)d_in[21];
    float* out = (float*)d_out;

    // layout (ushort units); Sb/Epre/PQb alias the Cs region (dead before k_cs)
    ushort_t* Abuf = (ushort_t*)d_ws;                   // 16384*1088      (35.7 MB)
    ushort_t* Wt   = Abuf + (size_t)ROWS * KP;          // 256*1088
    ushort_t* Wpq  = Wt + (size_t)256 * KP;             // 512*256
    ushort_t* Wca  = Wpq + (size_t)512 * 256;           // 384*256
    ushort_t* Wenc = Wca + (size_t)384 * 256;           // 256*256
    ushort_t* Co   = Wenc + (size_t)256 * 256;          // 114688*256     (58.7 MB)
    ushort_t* Cs   = Co + (size_t)PROWS * 256;          // 114688*256     (58.7 MB)
    float*    Srow = (float*)(Cs + (size_t)PROWS * 256);// 114688*32 f32  (14.7 MB)
    ushort_t* Sb   = Cs;                                // 16384*256  (aliased)
    ushort_t* Epre = Sb + (size_t)ROWS * 256;           // 16384*256  (aliased)
    ushort_t* PQb  = Epre + (size_t)ROWS * 256;         // 16384*512  (aliased)

    k_prep  <<<3456, 256, 0, stream>>>(out_W, core_W, ctx_W, att_W1, enc_W,
                                       state, x, Wt, Wpq, Wca, Wenc, Sb, Abuf);
    // Epre = state @ enc_W  (bf16 MFMA, N=256 resident, ping-pong)
    k_gemm_nres<4><<<ROWS / 64, 512, 0, stream>>>(Sb, 256, Wenc, 256, Epre, 256,
                                                  nullptr, 8, 256, 1);
    k_lnenc <<<ROWS / 4, 256, 0, stream>>>(Epre, enc_b, enc_g, enc_bt, Abuf);
    // PQb = s1 @ [W_top | W_bot]  (bf16 MFMA, N=512 resident, bf16 out)
    k_gemm_nres<8><<<ROWS / 64, 512, 0, stream>>>(Abuf, KP, Wpq, 256, PQb, PQS,
                                                  nullptr, 8, 512, 1);
    k_core  <<<ROWS / 4, 256, 0, stream>>>(PQb, core_b, core_g, core_bt, Co);
    // single-buffer GEMM + stats epilogue (z -> Cs, partial stats -> Srow)
    k_cs    <<<PROWS / 64, 512, 0, stream>>>(Co, Wca, ctx_b, att_b1, att_g,
                                             att_W2, Cs, Srow);
    // fold partials + gate + weighted sum -> eff
    k_eff2  <<<ROWS / 4, 256, 0, stream>>>(Cs, Srow, ctx_g, ctx_bt,
                                           att_g, att_bt, att_W2, att_b2, Abuf);
    // out = [s1 | eff | x] @ out_W + b  (bf16 MFMA, N=256 resident, ping-pong)
    k_gemm_nres<4><<<ROWS / 64, 512, 0, stream>>>(Abuf, KP, Wt, KP, out, H,
                                                  out_b, KP / 32, 250, 0);
}

// Round 12
// 334.326 us; speedup vs baseline: 1.3393x; 1.0038x over previous
//
#include <hip/hip_runtime.h>
#include <math.h>

#define KK 8
#define H 250          // SIZE == h1
#define MDIM 576
#define NB 2048
#define HA 100
#define ROWS (NB*KK)   // 16384
#define PROWS (ROWS*7) // 114688 pair rows
#define PQS 512        // PQb row stride (ushort): P at 0..249, Q at 256..505
#define KP 1088        // padded K for out GEMM (1076 -> 34*32)
#define EPS 1e-5f

typedef unsigned short ushort_t;
typedef short short8 __attribute__((ext_vector_type(8)));
typedef unsigned short us8 __attribute__((ext_vector_type(8)));
typedef unsigned short us4 __attribute__((ext_vector_type(4)));
typedef unsigned short us2 __attribute__((ext_vector_type(2)));
typedef float f32x4 __attribute__((ext_vector_type(4)));

// ---- DPP helpers (old=0 + bound_ctrl=1 so GCNDPPCombine folds to v_add_f32_dpp) ----
template<int CTRL>
__device__ __forceinline__ float dpp_add_f32(float x) {
    const int s = __builtin_amdgcn_update_dpp(
        0, __builtin_bit_cast(int, x), CTRL, 0xF, 0xF, true);
    return x + __builtin_bit_cast(float, s);
}
// full-wave (64-lane) sum; result broadcast wave-uniform via readlane(63)
__device__ __forceinline__ float wave_sum_dpp(float x) {
    x = dpp_add_f32<0x111>(x);  // row_shr:1
    x = dpp_add_f32<0x112>(x);  // row_shr:2
    x = dpp_add_f32<0x114>(x);  // row_shr:4
    x = dpp_add_f32<0x118>(x);  // row_shr:8
    x = dpp_add_f32<0x142>(x);  // row_bcast:15
    x = dpp_add_f32<0x143>(x);  // row_bcast:31 -> lane 63 holds total
    return __builtin_bit_cast(float, __builtin_amdgcn_readlane(
        __builtin_bit_cast(int, x), 63));
}
// 16-lane butterfly sum: result present in ALL 16 lanes of each 16-lane row
__device__ __forceinline__ float bfly16_sum(float x) {
    x = dpp_add_f32<0xB1>(x);   // quad_perm [1,0,3,2]  (xor 1)
    x = dpp_add_f32<0x4E>(x);   // quad_perm [2,3,0,1]  (xor 2)
    x = dpp_add_f32<0x141>(x);  // row_half_mirror      (pairs across quads)
    x = dpp_add_f32<0x140>(x);  // row_mirror           (pairs across halves)
    return x;
}

__device__ __forceinline__ void async_copy16(const void* g, void* l) {
    __builtin_amdgcn_global_load_lds(
        (const __attribute__((address_space(1))) void*)g,
        (__attribute__((address_space(3))) void*)l, 16, 0, 0);
}

__device__ __forceinline__ ushort_t f2bf(float v) {
    union { float f; unsigned int u; } c; c.f = v;
    unsigned int x = c.u;
    x += 0x7fff + ((x >> 16) & 1);   // RNE
    return (ushort_t)(x >> 16);
}
__device__ __forceinline__ float bf2f(ushort_t v) {
    union { unsigned int u; float f; } c; c.u = ((unsigned int)v) << 16;
    return c.f;
}
// fast tanh: 1 - 2/(exp(2x)+1)  (v_exp + v_rcp; ~1e-6 rel err, << bf16 ulp)
__device__ __forceinline__ float ftanh(float x) {
    const float e = __expf(2.f * x);
    return 1.f - 2.f * __builtin_amdgcn_rcpf(e + 1.f);
}
__device__ __forceinline__ float fsigmoid(float x) {
    return __builtin_amdgcn_rcpf(1.f + __expf(-x));
}

// ---- fused prep: Wt | Wpq | Wca | Wenc | Sb | x->Abuf (16 rows/block) ----
__global__ __launch_bounds__(256) void k_prep(
    const float* __restrict__ out_W, const float* __restrict__ core_W,
    const float* __restrict__ ctx_W, const float* __restrict__ att_W1,
    const float* __restrict__ enc_W, const float* __restrict__ state,
    const float* __restrict__ x,
    ushort_t* __restrict__ Wt, ushort_t* __restrict__ Wpq,
    ushort_t* __restrict__ Wca, ushort_t* __restrict__ Wenc,
    ushort_t* __restrict__ Sb, ushort_t* __restrict__ Abuf)
{
    const int b = blockIdx.x, t = threadIdx.x;
    if (b < 256) {                      // Wt[n][k] = out_W[k][n]
        const int n = b;
        for (int k = t; k < KP; k += 256) {
            const float v = (n < H && k < 1076) ? out_W[(size_t)k * H + n] : 0.f;
            Wt[(size_t)n * KP + k] = f2bf(v);
        }
    } else if (b < 768) {               // Wpq
        const int n = b - 256, k = t;
        float v = 0.f;
        if (k < H) {
            if (n < H)                    v = core_W[(size_t)k * H + n];
            else if (n >= 256 && n < 506) v = core_W[(size_t)(H + k) * H + (n - 256)];
        }
        Wpq[(size_t)n * 256 + k] = f2bf(v);
    } else if (b < 1152) {              // Wca
        const int n = b - 768, k = t;
        float v = 0.f;
        if (k < H) {
            if (n < H)           v = ctx_W[(size_t)k * H + n];
            else if (n < H + HA) v = att_W1[(size_t)k * HA + (n - H)];
        }
        Wca[(size_t)n * 256 + k] = f2bf(v);
    } else if (b < 1408) {              // Wenc[n][k] = enc_W[k][n]
        const int n = b - 1152, k = t;
        const float v = (n < H && k < H) ? enc_W[(size_t)k * H + n] : 0.f;
        Wenc[(size_t)n * 256 + k] = f2bf(v);
    } else if (b < 2432) {              // Sb: state padded to 256, bf16
        const int r0 = (b - 1408) * 16;
        for (int idx = t; idx < 16 * 256; idx += 256) {
            const int r = r0 + (idx >> 8), k = idx & 255;
            const float v = (k < H) ? state[(size_t)r * H + k] : 0.f;
            Sb[(size_t)r * 256 + k] = f2bf(v);
        }
    } else {                            // Abuf cols [500,1088): x + pad, 16 rows/block
        const int r0 = (b - 2432) * 16;
        for (int idx = t; idx < 16 * 588; idx += 256) {
            const int r = r0 + idx / 588, c = 500 + idx % 588;
            const float v = (c < 500 + MDIM) ? x[(size_t)r * MDIM + (c - 500)] : 0.f;
            Abuf[(size_t)r * KP + c] = f2bf(v);
        }
    }
}

// N-resident bf16 MFMA GEMM, M=32/block: C[m][n] = sum_k A[m][k]*B[n][k] (+bias).
// M=32 doubles the grid to ROWS/32 = 512 blocks = 2 blocks/CU (the M=64 grids
// were exactly 1 block/CU — no co-resident block to hide the stage drains;
// r10/r11 established occupancy > intra-block pipelining for these kernels).
// 8 waves = 2m x 4n, each wave 16 rows x NT*16 cols, acc[NT].
// NT<=4: ping-pong DB staging (36 KB LDS, 4-block cap holds).
// NT=8: single-buffer (34 KB), bounds (512,4) — acc[1][8]=32 regs fits 128.
template<int NT>
__global__ __launch_bounds__(512, 4) void k_gemm_nres(
    const ushort_t* __restrict__ A, int lda,
    const ushort_t* __restrict__ B, int ldb,
    void* __restrict__ Cp, int ldc,
    const float* __restrict__ bias,
    int ksteps, int nlim, int bf16out)
{
    constexpr bool DB = (NT <= 4);
    constexpr int NROWS = NT * 64;                    // B rows resident
    constexpr int ASZ = 32 * 32;                      // As elems per buffer (2 KB)
    constexpr int BSZ = NROWS * 32;                   // Bs elems per buffer
    __shared__ __align__(16) ushort_t As[(DB ? 2 : 1) * ASZ];
    __shared__ __align__(16) ushort_t Bs[(DB ? 2 : 1) * BSZ];
    const int tid = threadIdx.x, lane = tid & 63, wave = tid >> 6;
    const int wm = wave >> 2, wn = wave & 3;          // 2m x 4n
    const int R0 = (int)blockIdx.x * 32;

    const int ar = tid >> 2, acb = tid & 3;           // 128 threads stage 32 rows
    const bool aon = tid < 128;
    const int acl = acb ^ ((ar >> 1) & 3);
    const ushort_t* gA = A + (size_t)(R0 + ar) * lda + acl * 8;

    const int q = lane >> 4, fr = lane & 15;
    const int arow = wm * 16 + fr;                    // A-read row (0..31)

    f32x4 acc[NT] = {};

    if constexpr (DB) {
        auto stage = [&](int ks, int p) {
            const int k0 = ks * 32;
            if (aon) async_copy16(gA + k0, &As[p * ASZ + tid * 8]);
#pragma unroll
            for (int it = 0; it < NT / 2; ++it) {
                const int ci  = it * 512 + tid;
                const int rb  = ci >> 2, cb2 = ci & 3;
                const int clb = cb2 ^ ((rb >> 1) & 3);
                async_copy16(B + (size_t)rb * ldb + k0 + clb * 8,
                             &Bs[p * BSZ + ci * 8]);
            }
        };
        stage(0, 0);
        __syncthreads();           // drain buf0
        int p = 0;
        for (int ks = 0; ks < ksteps; ++ks) {
            if (ks + 1 < ksteps) stage(ks + 1, p ^ 1);   // async, overlaps MFMA
            const short8 a = *(const short8*)&As[p * ASZ +
                    (arow * 4 + (q ^ ((arow >> 1) & 3))) * 8];
#pragma unroll
            for (int nt = 0; nt < NT; ++nt) {
                const int n = wn * (NT * 16) + nt * 16 + fr;
                const short8 b = *(const short8*)&Bs[p * BSZ +
                        (n * 4 + (q ^ ((n >> 1) & 3))) * 8];
                acc[nt] = __builtin_amdgcn_mfma_f32_16x16x32_bf16(
                    a, b, acc[nt], 0, 0, 0);
            }
            __syncthreads();       // drains stage(ks+1); guards buf reuse
            p ^= 1;
        }
    } else {
        for (int ks = 0; ks < ksteps; ++ks) {
            const int k0 = ks * 32;
            if (aon) async_copy16(gA + k0, &As[tid * 8]);
#pragma unroll
            for (int it = 0; it < NT / 2; ++it) {
                const int ci  = it * 512 + tid;
                const int rb  = ci >> 2, cb2 = ci & 3;
                const int clb = cb2 ^ ((rb >> 1) & 3);
                async_copy16(B + (size_t)rb * ldb + k0 + clb * 8, &Bs[ci * 8]);
            }
            __syncthreads();
            const short8 a = *(const short8*)&As[
                    (arow * 4 + (q ^ ((arow >> 1) & 3))) * 8];
#pragma unroll
            for (int nt = 0; nt < NT; ++nt) {
                const int n = wn * (NT * 16) + nt * 16 + fr;
                const short8 b = *(const short8*)&Bs[(n * 4 + (q ^ ((n >> 1) & 3))) * 8];
                acc[nt] = __builtin_amdgcn_mfma_f32_16x16x32_bf16(
                    a, b, acc[nt], 0, 0, 0);
            }
            __syncthreads();
        }
    }

#pragma unroll
    for (int nt = 0; nt < NT; ++nt) {
        const int col = wn * (NT * 16) + nt * 16 + fr;
        if (col >= nlim) continue;
        const float bv = bias ? bias[col] : 0.f;
#pragma unroll
        for (int reg = 0; reg < 4; ++reg) {
            const int row = R0 + wm * 16 + q * 4 + reg;
            const float v = acc[nt][reg] + bv;
            if (bf16out) ((ushort_t*)Cp)[(size_t)row * ldc + col] = f2bf(v);
            else         ((float*)Cp)[(size_t)row * ldc + col] = v;
        }
    }
}

// LN(relu(Epre + enc_b)) -> Abuf cols [0,250). One wave per row, us4 loads.
__global__ __launch_bounds__(256) void k_lnenc(const ushort_t* __restrict__ Epre,
    const float* __restrict__ eb, const float* __restrict__ eg,
    const float* __restrict__ ebt, ushort_t* __restrict__ Abuf)
{
    const int wave = threadIdx.x >> 6, lane = threadIdx.x & 63;
    const int row = blockIdx.x * 4 + wave;
    const int c0 = 4 * lane;

    const us4 v = *(const us4*)&Epre[(size_t)row * 256 + c0];
    float y[4]; float sm = 0.f, sq = 0.f;
#pragma unroll
    for (int t = 0; t < 4; ++t) {
        const int cc = c0 + t;
        float z = 0.f;
        if (cc < H) z = fmaxf(bf2f(v[t]) + eb[cc], 0.f);
        y[t] = z; sm += z; sq += z * z;
    }
    sm = wave_sum_dpp(sm);
    sq = wave_sum_dpp(sq);
    const float mu = sm * (1.f / H);
    const float rs = __builtin_amdgcn_rsqf(sq * (1.f / H) - mu * mu + EPS);
    ushort_t o[4];
#pragma unroll
    for (int t = 0; t < 4; ++t) {
        const int cc = c0 + t;
        o[t] = (cc < H) ? f2bf((y[t] - mu) * rs * eg[cc] + ebt[cc]) : (ushort_t)0;
    }
    ushort_t* dst = Abuf + (size_t)row * KP + c0;
    if (c0 + 3 < H) { *(us4*)dst = (us4){o[0], o[1], o[2], o[3]}; }
    else {
        if (c0 + 1 < H) *(us2*)dst = (us2){o[0], o[1]};
    }
}

// Co[r][0:256] = LN(relu(P_g + Q_qr + core_b)) bf16. One wave per GROUP.
__global__ __launch_bounds__(256) void k_core(const ushort_t* __restrict__ PQb,
    const float* __restrict__ core_b, const float* __restrict__ core_g,
    const float* __restrict__ core_bt, ushort_t* __restrict__ Co)
{
    const int wave = threadIdx.x >> 6, lane = threadIdx.x & 63;
    const int g = blockIdx.x * 4 + wave;        // group 0..16383
    const int i = g & 7;
    const int c = lane * 4;

    const us4 pu = *(const us4*)&PQb[(size_t)g * PQS + c];
    us4 qu[7];
#pragma unroll
    for (int jj = 0; jj < 7; ++jj) {
        const int j = jj + (jj >= i ? 1 : 0);
        const int qr = (g & ~7) + j;
        qu[jj] = *(const us4*)&PQb[(size_t)qr * PQS + 256 + c];
    }
    float pe[4], cb[4], cg[4], cbt[4]; bool vl[4];
#pragma unroll
    for (int t = 0; t < 4; ++t) {
        vl[t]  = (c + t) < H;
        pe[t]  = bf2f(pu[t]);
        cb[t]  = vl[t] ? core_b[c + t]  : 0.f;
        cg[t]  = vl[t] ? core_g[c + t]  : 0.f;
        cbt[t] = vl[t] ? core_bt[c + t] : 0.f;
    }
    float z[7][4], red[7][2];
#pragma unroll
    for (int jj = 0; jj < 7; ++jj) {
        float sm = 0.f, sq = 0.f;
#pragma unroll
        for (int t = 0; t < 4; ++t) {
            const float zz = vl[t] ? fmaxf(pe[t] + bf2f(qu[jj][t]) + cb[t], 0.f) : 0.f;
            z[jj][t] = zz; sm += zz; sq = fmaf(zz, zz, sq);
        }
        red[jj][0] = sm; red[jj][1] = sq;
    }
#pragma unroll
    for (int jj = 0; jj < 7; ++jj) {
        red[jj][0] = wave_sum_dpp(red[jj][0]);
        red[jj][1] = wave_sum_dpp(red[jj][1]);
    }
#pragma unroll
    for (int jj = 0; jj < 7; ++jj) {
        const float mu = red[jj][0] * (1.f / H);
        const float rs = __builtin_amdgcn_rsqf(red[jj][1] * (1.f / H) - mu * mu + EPS);
        us4 o;
#pragma unroll
        for (int t = 0; t < 4; ++t)
            o[t] = vl[t] ? f2bf((z[jj][t] - mu) * rs * cg[t] + cbt[t]) : (ushort_t)0;
        *(us4*)&Co[((size_t)g * 7 + jj) * 256 + c] = o;
    }
}

// ================= k_cs: single-buffer GEMM + register-only stats epilogue ==
// GEMM = r8 k_cs verbatim (LDS 28.6 KB, 4 blocks/CU, 1792 blocks = 7/CU).
// r10's ping-pong REGRESSED 63->86 us — occupancy beats intra-block
// pipelining for this latency-bound kernel. DO NOT add LDS here.
// Epilogue (regs + bfly16 only): z -> Cs[row][256], partial stats -> Srow.
__global__ __launch_bounds__(512, 4) void k_cs(
    const ushort_t* __restrict__ Co,
    const ushort_t* __restrict__ Wca,   // [384][256] bf16
    const float* __restrict__ ctx_b,
    const float* __restrict__ att_b1, const float* __restrict__ att_g,
    const float* __restrict__ attW2,
    ushort_t* __restrict__ Cs, float* __restrict__ Srow)
{
    __shared__ __align__(16) ushort_t As[64 * 32];    // 4096 B
    __shared__ __align__(16) ushort_t Bs[384 * 32];   // 24576 B
    const int tid = threadIdx.x, lane = tid & 63, wave = tid >> 6;
    const int wmm = wave >> 2, wnn = wave & 3;
    const int R0 = (int)blockIdx.x * 64;

    const int ar = tid >> 2, acb = tid & 3;
    const bool aon = tid < 256;
    const int acl = acb ^ ((ar >> 1) & 3);
    const ushort_t* gA = Co + (size_t)(R0 + ar) * 256 + acl * 8;

    const int q = lane >> 4, fr = lane & 15;

    f32x4 acc[2][6] = {};
    for (int ks = 0; ks < 8; ++ks) {
        const int k0 = ks * 32;
        if (aon) async_copy16(gA + k0, &As[tid * 8]);
#pragma unroll
        for (int it = 0; it < 3; ++it) {
            const int ci  = it * 512 + tid;
            const int rb  = ci >> 2, cb2 = ci & 3;
            const int clb = cb2 ^ ((rb >> 1) & 3);
            async_copy16(Wca + (size_t)rb * 256 + k0 + clb * 8, &Bs[ci * 8]);
        }
        __syncthreads();
        short8 a[2];
#pragma unroll
        for (int ms = 0; ms < 2; ++ms) {
            const int row = wmm * 32 + ms * 16 + fr;
            a[ms] = *(const short8*)&As[(row * 4 + (q ^ ((row >> 1) & 3))) * 8];
        }
#pragma unroll
        for (int nt = 0; nt < 6; ++nt) {
            const int n = wnn * 96 + nt * 16 + fr;
            const short8 b = *(const short8*)&Bs[(n * 4 + (q ^ ((n >> 1) & 3))) * 8];
#pragma unroll
            for (int ms = 0; ms < 2; ++ms)
                acc[ms][nt] = __builtin_amdgcn_mfma_f32_16x16x32_bf16(
                    a[ms], b, acc[ms][nt], 0, 0, 0);
        }
        __syncthreads();
    }

    // ---- epilogue: per-col consts (loaded now; keeps GEMM regs unchanged) ----
    bool eC[6], eA[6]; float b_[6], gw[6];
#pragma unroll
    for (int nt = 0; nt < 6; ++nt) {
        const int col = wnn * 96 + nt * 16 + fr;
        eC[nt] = col < H;
        eA[nt] = (col >= H) && (col < H + HA);
        if (eC[nt])      { b_[nt] = ctx_b[col];      gw[nt] = 0.f; }
        else if (eA[nt]) { const int ca = col - H;
                           b_[nt] = att_b1[ca];
                           gw[nt] = att_g[ca] * attW2[ca]; }
        else             { b_[nt] = gw[nt] = 0.f; }
    }

    // per-ms pass bounds live registers (r8-proven transform)
#pragma unroll
    for (int ms = 0; ms < 2; ++ms) {
        float smc[4] = {}, sqc[4] = {}, sma[4] = {}, sqa[4] = {}, szgw[4] = {};
#pragma unroll
        for (int nt = 0; nt < 6; ++nt) {
#pragma unroll
            for (int reg = 0; reg < 4; ++reg) {
                const float val = acc[ms][nt][reg] + b_[nt];
                if (eC[nt]) {
                    const float zz = fmaxf(val, 0.f);
                    acc[ms][nt][reg] = zz;
                    smc[reg] += zz; sqc[reg] = fmaf(zz, zz, sqc[reg]);
                } else if (eA[nt]) {
                    const float za = ftanh(val);
                    sma[reg] += za; sqa[reg] = fmaf(za, za, sqa[reg]);
                    szgw[reg] = fmaf(za, gw[nt], szgw[reg]);
                }
            }
        }
#pragma unroll
        for (int reg = 0; reg < 4; ++reg) {
            smc[reg]  = bfly16_sum(smc[reg]);
            sqc[reg]  = bfly16_sum(sqc[reg]);
            sma[reg]  = bfly16_sum(sma[reg]);
            sqa[reg]  = bfly16_sum(sqa[reg]);
            szgw[reg] = bfly16_sum(szgw[reg]);
        }
        if (fr == 0) {
#pragma unroll
            for (int reg = 0; reg < 4; ++reg) {
                const int row = R0 + wmm * 32 + ms * 16 + q * 4 + reg;
                *(f32x4*)&Srow[(size_t)row * 32 + wnn * 8] =
                    (f32x4){smc[reg], sqc[reg], sma[reg], sqa[reg]};
                Srow[(size_t)row * 32 + wnn * 8 + 4] = szgw[reg];
            }
        }
        // write z (relu'd ctx) to Cs cols [0,256); att cols 250..255 get 0
#pragma unroll
        for (int nt = 0; nt < 6; ++nt) {
            const int col = wnn * 96 + nt * 16 + fr;
            if (col >= 256) continue;
#pragma unroll
            for (int reg = 0; reg < 4; ++reg) {
                const int row = R0 + wmm * 32 + ms * 16 + q * 4 + reg;
                Cs[(size_t)row * 256 + col] =
                    eC[nt] ? f2bf(acc[ms][nt][reg]) : (ushort_t)0;
            }
        }
    }
}

// ================= k_eff2: fold partials + gate + weighted sum =================
// One wave per group. Pure streaming: reads 7x256 z (bf16) + 7x20 scalars.
__global__ __launch_bounds__(256) void k_eff2(
    const ushort_t* __restrict__ Cs, const float* __restrict__ Srow,
    const float* __restrict__ ctx_g, const float* __restrict__ ctx_bt,
    const float* __restrict__ att_g, const float* __restrict__ att_bt,
    const float* __restrict__ attW2, const float* __restrict__ att_b2,
    ushort_t* __restrict__ Abuf)
{
    const int wave = threadIdx.x >> 6, lane = threadIdx.x & 63;
    const int g = blockIdx.x * 4 + wave;
    const int c0 = 4 * lane;

    // row-invariant attention sums
    float psg = 0.f, psb = 0.f;
    for (int c = lane; c < HA; c += 64) {
        const float w2 = attW2[c];
        psg = fmaf(att_g[c], w2, psg);
        psb = fmaf(att_bt[c], w2, psb);
    }
    psg = wave_sum_dpp(psg); psb = wave_sum_dpp(psb);
    const float sgw = psg;
    const float ab2 = att_b2[0] + psb;

    float g4[4], bt4[4];
#pragma unroll
    for (int t = 0; t < 4; ++t) {
        const bool vl = (c0 + t) < H;
        g4[t]  = vl ? ctx_g[c0 + t]  : 0.f;
        bt4[t] = vl ? ctx_bt[c0 + t] : 0.f;
    }

    // prefetch z rows
    us4 zv[7];
#pragma unroll
    for (int jj = 0; jj < 7; ++jj)
        zv[jj] = *(const us4*)&Cs[((size_t)g * 7 + jj) * 256 + c0];

    float A4[4] = {0.f, 0.f, 0.f, 0.f};
    float S0 = 0.f, S1 = 0.f;
#pragma unroll
    for (int jj = 0; jj < 7; ++jj) {
        const float* sr = Srow + ((size_t)g * 7 + jj) * 32;
        float s0 = 0.f, s1 = 0.f, s2 = 0.f, s3 = 0.f, s4 = 0.f;
#pragma unroll
        for (int w = 0; w < 4; ++w) {
            const f32x4 v = *(const f32x4*)&sr[w * 8];
            s0 += v[0]; s1 += v[1]; s2 += v[2]; s3 += v[3];
            s4 += sr[w * 8 + 4];
        }
        const float muC = s0 * (1.f / H);
        const float rsC = __builtin_amdgcn_rsqf(s1 * (1.f / H) - muC * muC + EPS);
        const float muA = s2 * (1.f / HA);
        const float rsA = __builtin_amdgcn_rsqf(s3 * (1.f / HA) - muA * muA + EPS);
        const float dot = rsA * (s4 - muA * sgw) + ab2;
        const float ag  = fsigmoid(dot);
        const float cj  = ag * rsC;
        S0 += ag; S1 = fmaf(cj, muC, S1);
#pragma unroll
        for (int e = 0; e < 4; ++e)
            A4[e] = fmaf(cj, bf2f(zv[jj][e]), A4[e]);
    }
    ushort_t o[4];
#pragma unroll
    for (int e = 0; e < 4; ++e)
        o[e] = f2bf(g4[e] * (A4[e] - S1) + bt4[e] * S0);
    ushort_t* dst = Abuf + (size_t)g * KP + H + c0;
    if (c0 + 1 < H) *(us2*)dst       = (us2){o[0], o[1]};
    if (c0 + 3 < H) *(us2*)(dst + 2) = (us2){o[2], o[3]};
}

extern "C" void kernel_launch(void* const* d_in, const int* in_sizes, int n_in,
                              void* d_out, int out_size, void* d_ws, size_t ws_size,
                              hipStream_t stream)
{
    const float* x      = (const float*)d_in[0];
    const float* state  = (const float*)d_in[1];
    const float* enc_W  = (const float*)d_in[2];
    const float* enc_b  = (const float*)d_in[3];
    const float* enc_g  = (const float*)d_in[4];
    const float* enc_bt = (const float*)d_in[5];
    const float* core_W = (const float*)d_in[6];
    const float* core_b = (const float*)d_in[7];
    const float* core_g = (const float*)d_in[8];
    const float* core_bt= (const float*)d_in[9];
    const float* ctx_W  = (const float*)d_in[10];
    const float* ctx_b  = (const float*)d_in[11];
    const float* ctx_g  = (const float*)d_in[12];
    const float* ctx_bt = (const float*)d_in[13];
    const float* att_W1 = (const float*)d_in[14];
    const float* att_b1 = (const float*)d_in[15];
    const float* att_g  = (const float*)d_in[16];
    const float* att_bt = (const float*)d_in[17];
    const float* att_W2 = (const float*)d_in[18];
    const float* att_b2 = (const float*)d_in[19];
    const float* out_W  = (const float*)d_in[20];
    const float* out_b  = (const float*)d_in[21];
    float* out = (float*)d_out;

    // layout (ushort units); Sb/Epre/PQb alias the Cs region (dead before k_cs)
    ushort_t* Abuf = (ushort_t*)d_ws;                   // 16384*1088      (35.7 MB)
    ushort_t* Wt   = Abuf + (size_t)ROWS * KP;          // 256*1088
    ushort_t* Wpq  = Wt + (size_t)256 * KP;             // 512*256
    ushort_t* Wca  = Wpq + (size_t)512 * 256;           // 384*256
    ushort_t* Wenc = Wca + (size_t)384 * 256;           // 256*256
    ushort_t* Co   = Wenc + (size_t)256 * 256;          // 114688*256     (58.7 MB)
    ushort_t* Cs   = Co + (size_t)PROWS * 256;          // 114688*256     (58.7 MB)
    float*    Srow = (float*)(Cs + (size_t)PROWS * 256);// 114688*32 f32  (14.7 MB)
    ushort_t* Sb   = Cs;                                // 16384*256  (aliased)
    ushort_t* Epre = Sb + (size_t)ROWS * 256;           // 16384*256  (aliased)
    ushort_t* PQb  = Epre + (size_t)ROWS * 256;         // 16384*512  (aliased)

    k_prep  <<<3456, 256, 0, stream>>>(out_W, core_W, ctx_W, att_W1, enc_W,
                                       state, x, Wt, Wpq, Wca, Wenc, Sb, Abuf);
    // Epre = state @ enc_W  (bf16 MFMA, N=256 resident, M=32, ping-pong)
    k_gemm_nres<4><<<ROWS / 32, 512, 0, stream>>>(Sb, 256, Wenc, 256, Epre, 256,
                                                  nullptr, 8, 256, 1);
    k_lnenc <<<ROWS / 4, 256, 0, stream>>>(Epre, enc_b, enc_g, enc_bt, Abuf);
    // PQb = s1 @ [W_top | W_bot]  (bf16 MFMA, N=512 resident, M=32, bf16 out)
    k_gemm_nres<8><<<ROWS / 32, 512, 0, stream>>>(Abuf, KP, Wpq, 256, PQb, PQS,
                                                  nullptr, 8, 512, 1);
    k_core  <<<ROWS / 4, 256, 0, stream>>>(PQb, core_b, core_g, core_bt, Co);
    // single-buffer GEMM + stats epilogue (z -> Cs, partial stats -> Srow)
    k_cs    <<<PROWS / 64, 512, 0, stream>>>(Co, Wca, ctx_b, att_b1, att_g,
                                             att_W2, Cs, Srow);
    // fold partials + gate + weighted sum -> eff
    k_eff2  <<<ROWS / 4, 256, 0, stream>>>(Cs, Srow, ctx_g, ctx_bt,
                                           att_g, att_bt, att_W2, att_b2, Abuf);
    // out = [s1 | eff | x] @ out_W + b  (bf16 MFMA, N=256, M=32, ping-pong)
    k_gemm_nres<4><<<ROWS / 32, 512, 0, stream>>>(Abuf, KP, Wt, KP, out, H,
                                                  out_b, KP / 32, 250, 0);
}

// Round 13
// 319.245 us; speedup vs baseline: 1.4026x; 1.0472x over previous
//
#include <hip/hip_runtime.h>
#include <math.h>

#define KK 8
#define H 250          // SIZE == h1
#define MDIM 576
#define NB 2048
#define HA 100
#define ROWS (NB*KK)   // 16384
#define PROWS (ROWS*7) // 114688 pair rows
#define PQS 512        // PQb row stride (ushort): P at 0..249, Q at 256..505
#define KP 1088        // padded K for out GEMM (1076 -> 34*32)
#define EPS 1e-5f

typedef unsigned short ushort_t;
typedef short short8 __attribute__((ext_vector_type(8)));
typedef unsigned short us8 __attribute__((ext_vector_type(8)));
typedef unsigned short us4 __attribute__((ext_vector_type(4)));
typedef unsigned short us2 __attribute__((ext_vector_type(2)));
typedef float f32x4 __attribute__((ext_vector_type(4)));

// ---- DPP helpers (old=0 + bound_ctrl=1 so GCNDPPCombine folds to v_add_f32_dpp) ----
template<int CTRL>
__device__ __forceinline__ float dpp_add_f32(float x) {
    const int s = __builtin_amdgcn_update_dpp(
        0, __builtin_bit_cast(int, x), CTRL, 0xF, 0xF, true);
    return x + __builtin_bit_cast(float, s);
}
// full-wave (64-lane) sum; result broadcast wave-uniform via readlane(63)
__device__ __forceinline__ float wave_sum_dpp(float x) {
    x = dpp_add_f32<0x111>(x);  // row_shr:1
    x = dpp_add_f32<0x112>(x);  // row_shr:2
    x = dpp_add_f32<0x114>(x);  // row_shr:4
    x = dpp_add_f32<0x118>(x);  // row_shr:8
    x = dpp_add_f32<0x142>(x);  // row_bcast:15
    x = dpp_add_f32<0x143>(x);  // row_bcast:31 -> lane 63 holds total
    return __builtin_bit_cast(float, __builtin_amdgcn_readlane(
        __builtin_bit_cast(int, x), 63));
}
// 16-lane butterfly sum: result present in ALL 16 lanes of each 16-lane row
__device__ __forceinline__ float bfly16_sum(float x) {
    x = dpp_add_f32<0xB1>(x);   // quad_perm [1,0,3,2]  (xor 1)
    x = dpp_add_f32<0x4E>(x);   // quad_perm [2,3,0,1]  (xor 2)
    x = dpp_add_f32<0x141>(x);  // row_half_mirror      (pairs across quads)
    x = dpp_add_f32<0x140>(x);  // row_mirror           (pairs across halves)
    return x;
}

__device__ __forceinline__ void async_copy16(const void* g, void* l) {
    __builtin_amdgcn_global_load_lds(
        (const __attribute__((address_space(1))) void*)g,
        (__attribute__((address_space(3))) void*)l, 16, 0, 0);
}

__device__ __forceinline__ ushort_t f2bf(float v) {
    union { float f; unsigned int u; } c; c.f = v;
    unsigned int x = c.u;
    x += 0x7fff + ((x >> 16) & 1);   // RNE
    return (ushort_t)(x >> 16);
}
__device__ __forceinline__ float bf2f(ushort_t v) {
    union { unsigned int u; float f; } c; c.u = ((unsigned int)v) << 16;
    return c.f;
}
// fast tanh: 1 - 2/(exp(2x)+1)  (v_exp + v_rcp; ~1e-6 rel err, << bf16 ulp)
__device__ __forceinline__ float ftanh(float x) {
    const float e = __expf(2.f * x);
    return 1.f - 2.f * __builtin_amdgcn_rcpf(e + 1.f);
}
__device__ __forceinline__ float fsigmoid(float x) {
    return __builtin_amdgcn_rcpf(1.f + __expf(-x));
}

// ---- fused prep: Wt | Wpq | Wca | Wenc | Sb | x->Abuf (16 rows/block) ----
__global__ __launch_bounds__(256) void k_prep(
    const float* __restrict__ out_W, const float* __restrict__ core_W,
    const float* __restrict__ ctx_W, const float* __restrict__ att_W1,
    const float* __restrict__ enc_W, const float* __restrict__ state,
    const float* __restrict__ x,
    ushort_t* __restrict__ Wt, ushort_t* __restrict__ Wpq,
    ushort_t* __restrict__ Wca, ushort_t* __restrict__ Wenc,
    ushort_t* __restrict__ Sb, ushort_t* __restrict__ Abuf)
{
    const int b = blockIdx.x, t = threadIdx.x;
    if (b < 256) {                      // Wt[n][k] = out_W[k][n]
        const int n = b;
        for (int k = t; k < KP; k += 256) {
            const float v = (n < H && k < 1076) ? out_W[(size_t)k * H + n] : 0.f;
            Wt[(size_t)n * KP + k] = f2bf(v);
        }
    } else if (b < 768) {               // Wpq
        const int n = b - 256, k = t;
        float v = 0.f;
        if (k < H) {
            if (n < H)                    v = core_W[(size_t)k * H + n];
            else if (n >= 256 && n < 506) v = core_W[(size_t)(H + k) * H + (n - 256)];
        }
        Wpq[(size_t)n * 256 + k] = f2bf(v);
    } else if (b < 1152) {              // Wca
        const int n = b - 768, k = t;
        float v = 0.f;
        if (k < H) {
            if (n < H)           v = ctx_W[(size_t)k * H + n];
            else if (n < H + HA) v = att_W1[(size_t)k * HA + (n - H)];
        }
        Wca[(size_t)n * 256 + k] = f2bf(v);
    } else if (b < 1408) {              // Wenc[n][k] = enc_W[k][n]
        const int n = b - 1152, k = t;
        const float v = (n < H && k < H) ? enc_W[(size_t)k * H + n] : 0.f;
        Wenc[(size_t)n * 256 + k] = f2bf(v);
    } else if (b < 2432) {              // Sb: state padded to 256, bf16
        const int r0 = (b - 1408) * 16;
        for (int idx = t; idx < 16 * 256; idx += 256) {
            const int r = r0 + (idx >> 8), k = idx & 255;
            const float v = (k < H) ? state[(size_t)r * H + k] : 0.f;
            Sb[(size_t)r * 256 + k] = f2bf(v);
        }
    } else {                            // Abuf cols [500,1088): x + pad, 16 rows/block
        const int r0 = (b - 2432) * 16;
        for (int idx = t; idx < 16 * 588; idx += 256) {
            const int r = r0 + idx / 588, c = 500 + idx % 588;
            const float v = (c < 500 + MDIM) ? x[(size_t)r * MDIM + (c - 500)] : 0.f;
            Abuf[(size_t)r * KP + c] = f2bf(v);
        }
    }
}

// N-resident bf16 MFMA GEMM, M=32/block: C[m][n] = sum_k A[m][k]*B[n][k] (+bias).
// M=32: 2 blocks/CU for ROWS-sized grids. 8 waves = 2m x 4n, acc[NT].
// NT<=4: ping-pong DB staging. NT=8: single-buffer.
template<int NT>
__global__ __launch_bounds__(512, 4) void k_gemm_nres(
    const ushort_t* __restrict__ A, int lda,
    const ushort_t* __restrict__ B, int ldb,
    void* __restrict__ Cp, int ldc,
    const float* __restrict__ bias,
    int ksteps, int nlim, int bf16out)
{
    constexpr bool DB = (NT <= 4);
    constexpr int NROWS = NT * 64;                    // B rows resident
    constexpr int ASZ = 32 * 32;                      // As elems per buffer (2 KB)
    constexpr int BSZ = NROWS * 32;                   // Bs elems per buffer
    __shared__ __align__(16) ushort_t As[(DB ? 2 : 1) * ASZ];
    __shared__ __align__(16) ushort_t Bs[(DB ? 2 : 1) * BSZ];
    const int tid = threadIdx.x, lane = tid & 63, wave = tid >> 6;
    const int wm = wave >> 2, wn = wave & 3;          // 2m x 4n
    const int R0 = (int)blockIdx.x * 32;

    const int ar = tid >> 2, acb = tid & 3;           // 128 threads stage 32 rows
    const bool aon = tid < 128;
    const int acl = acb ^ ((ar >> 1) & 3);
    const ushort_t* gA = A + (size_t)(R0 + ar) * lda + acl * 8;

    const int q = lane >> 4, fr = lane & 15;
    const int arow = wm * 16 + fr;                    // A-read row (0..31)

    f32x4 acc[NT] = {};

    if constexpr (DB) {
        auto stage = [&](int ks, int p) {
            const int k0 = ks * 32;
            if (aon) async_copy16(gA + k0, &As[p * ASZ + tid * 8]);
#pragma unroll
            for (int it = 0; it < NT / 2; ++it) {
                const int ci  = it * 512 + tid;
                const int rb  = ci >> 2, cb2 = ci & 3;
                const int clb = cb2 ^ ((rb >> 1) & 3);
                async_copy16(B + (size_t)rb * ldb + k0 + clb * 8,
                             &Bs[p * BSZ + ci * 8]);
            }
        };
        stage(0, 0);
        __syncthreads();           // drain buf0
        int p = 0;
        for (int ks = 0; ks < ksteps; ++ks) {
            if (ks + 1 < ksteps) stage(ks + 1, p ^ 1);   // async, overlaps MFMA
            const short8 a = *(const short8*)&As[p * ASZ +
                    (arow * 4 + (q ^ ((arow >> 1) & 3))) * 8];
#pragma unroll
            for (int nt = 0; nt < NT; ++nt) {
                const int n = wn * (NT * 16) + nt * 16 + fr;
                const short8 b = *(const short8*)&Bs[p * BSZ +
                        (n * 4 + (q ^ ((n >> 1) & 3))) * 8];
                acc[nt] = __builtin_amdgcn_mfma_f32_16x16x32_bf16(
                    a, b, acc[nt], 0, 0, 0);
            }
            __syncthreads();       // drains stage(ks+1); guards buf reuse
            p ^= 1;
        }
    } else {
        for (int ks = 0; ks < ksteps; ++ks) {
            const int k0 = ks * 32;
            if (aon) async_copy16(gA + k0, &As[tid * 8]);
#pragma unroll
            for (int it = 0; it < NT / 2; ++it) {
                const int ci  = it * 512 + tid;
                const int rb  = ci >> 2, cb2 = ci & 3;
                const int clb = cb2 ^ ((rb >> 1) & 3);
                async_copy16(B + (size_t)rb * ldb + k0 + clb * 8, &Bs[ci * 8]);
            }
            __syncthreads();
            const short8 a = *(const short8*)&As[
                    (arow * 4 + (q ^ ((arow >> 1) & 3))) * 8];
#pragma unroll
            for (int nt = 0; nt < NT; ++nt) {
                const int n = wn * (NT * 16) + nt * 16 + fr;
                const short8 b = *(const short8*)&Bs[(n * 4 + (q ^ ((n >> 1) & 3))) * 8];
                acc[nt] = __builtin_amdgcn_mfma_f32_16x16x32_bf16(
                    a, b, acc[nt], 0, 0, 0);
            }
            __syncthreads();
        }
    }

#pragma unroll
    for (int nt = 0; nt < NT; ++nt) {
        const int col = wn * (NT * 16) + nt * 16 + fr;
        if (col >= nlim) continue;
        const float bv = bias ? bias[col] : 0.f;
#pragma unroll
        for (int reg = 0; reg < 4; ++reg) {
            const int row = R0 + wm * 16 + q * 4 + reg;
            const float v = acc[nt][reg] + bv;
            if (bf16out) ((ushort_t*)Cp)[(size_t)row * ldc + col] = f2bf(v);
            else         ((float*)Cp)[(size_t)row * ldc + col] = v;
        }
    }
}

// ================= k_encln: enc GEMM + fused LN epilogue ==================
// = r12 DB GEMM (NT=4, M=32) + in-block LN(relu(.+eb)) -> Abuf cols [0,250).
// Block holds FULL rows (N=256 resident) so LN is local. Epilogue LDS
// (red[32][8], scal[32][2]) ALIASES Bs — dead after the ks loop's final
// barrier — so LDS stays 36 KB (occupancy unchanged). Deletes k_lnenc +
// the 16 MB Epre round-trip.
__global__ __launch_bounds__(512, 4) void k_encln(
    const ushort_t* __restrict__ Sb,     // [ROWS][256] bf16
    const ushort_t* __restrict__ Wenc,   // [256][256] bf16
    const float* __restrict__ eb, const float* __restrict__ eg,
    const float* __restrict__ ebt,
    ushort_t* __restrict__ Abuf)
{
    constexpr int ASZ = 32 * 32;      // 1024 elems = 2 KB
    constexpr int BSZ = 256 * 32;     // 8192 elems = 16 KB
    __shared__ __align__(16) ushort_t As[2 * ASZ];
    __shared__ __align__(16) ushort_t Bs[2 * BSZ];
    const int tid = threadIdx.x, lane = tid & 63, wave = tid >> 6;
    const int wm = wave >> 2, wn = wave & 3;
    const int R0 = (int)blockIdx.x * 32;

    const int ar = tid >> 2, acb = tid & 3;
    const bool aon = tid < 128;
    const int acl = acb ^ ((ar >> 1) & 3);
    const ushort_t* gA = Sb + (size_t)(R0 + ar) * 256 + acl * 8;

    const int q = lane >> 4, fr = lane & 15;
    const int arow = wm * 16 + fr;

    auto stage = [&](int ks, int p) {
        const int k0 = ks * 32;
        if (aon) async_copy16(gA + k0, &As[p * ASZ + tid * 8]);
#pragma unroll
        for (int it = 0; it < 2; ++it) {
            const int ci  = it * 512 + tid;
            const int rb  = ci >> 2, cb2 = ci & 3;
            const int clb = cb2 ^ ((rb >> 1) & 3);
            async_copy16(Wenc + (size_t)rb * 256 + k0 + clb * 8,
                         &Bs[p * BSZ + ci * 8]);
        }
    };

    f32x4 acc[4] = {};
    stage(0, 0);
    __syncthreads();
    int p = 0;
    for (int ks = 0; ks < 8; ++ks) {
        if (ks + 1 < 8) stage(ks + 1, p ^ 1);
        const short8 a = *(const short8*)&As[p * ASZ +
                (arow * 4 + (q ^ ((arow >> 1) & 3))) * 8];
#pragma unroll
        for (int nt = 0; nt < 4; ++nt) {
            const int n = wn * 64 + nt * 16 + fr;
            const short8 b = *(const short8*)&Bs[p * BSZ +
                    (n * 4 + (q ^ ((n >> 1) & 3))) * 8];
            acc[nt] = __builtin_amdgcn_mfma_f32_16x16x32_bf16(a, b, acc[nt], 0, 0, 0);
        }
        __syncthreads();    // last iter: all Bs reads done -> Bs reusable
        p ^= 1;
    }

    // ---- LN epilogue (LDS aliased onto Bs) ----
    float* red  = (float*)Bs;          // [32][8]: row-major, {sm,sq} per wn
    float* scal = (float*)Bs + 256;    // [32][2]: {mu, rs}

    float y[4][4]; float sm[4] = {}, sq[4] = {};
#pragma unroll
    for (int nt = 0; nt < 4; ++nt) {
        const int col = wn * 64 + nt * 16 + fr;
        const float ebv = (col < H) ? eb[col] : 0.f;
#pragma unroll
        for (int reg = 0; reg < 4; ++reg) {
            float z = 0.f;
            if (col < H) z = fmaxf(acc[nt][reg] + ebv, 0.f);
            y[nt][reg] = z; sm[reg] += z; sq[reg] = fmaf(z, z, sq[reg]);
        }
    }
#pragma unroll
    for (int reg = 0; reg < 4; ++reg) {
        sm[reg] = bfly16_sum(sm[reg]);
        sq[reg] = bfly16_sum(sq[reg]);
    }
    if (fr == 0) {
#pragma unroll
        for (int reg = 0; reg < 4; ++reg) {
            const int row = wm * 16 + q * 4 + reg;
            red[row * 8 + wn * 2]     = sm[reg];
            red[row * 8 + wn * 2 + 1] = sq[reg];
        }
    }
    __syncthreads();
    if (wave == 0 && lane < 32) {
        const float s0 = red[lane * 8]     + red[lane * 8 + 2] +
                         red[lane * 8 + 4] + red[lane * 8 + 6];
        const float s1 = red[lane * 8 + 1] + red[lane * 8 + 3] +
                         red[lane * 8 + 5] + red[lane * 8 + 7];
        const float mu = s0 * (1.f / H);
        const float rs = __builtin_amdgcn_rsqf(s1 * (1.f / H) - mu * mu + EPS);
        scal[lane * 2]     = mu;
        scal[lane * 2 + 1] = rs;
    }
    __syncthreads();
#pragma unroll
    for (int nt = 0; nt < 4; ++nt) {
        const int col = wn * 64 + nt * 16 + fr;
        if (col >= H) continue;
        const float egv = eg[col], ebtv = ebt[col];
#pragma unroll
        for (int reg = 0; reg < 4; ++reg) {
            const int row = wm * 16 + q * 4 + reg;
            const float mu = scal[row * 2], rs = scal[row * 2 + 1];
            Abuf[(size_t)(R0 + row) * KP + col] =
                f2bf((y[nt][reg] - mu) * rs * egv + ebtv);
        }
    }
}

// Co[r][0:256] = LN(relu(P_g + Q_qr + core_b)) bf16. One wave per GROUP.
__global__ __launch_bounds__(256) void k_core(const ushort_t* __restrict__ PQb,
    const float* __restrict__ core_b, const float* __restrict__ core_g,
    const float* __restrict__ core_bt, ushort_t* __restrict__ Co)
{
    const int wave = threadIdx.x >> 6, lane = threadIdx.x & 63;
    const int g = blockIdx.x * 4 + wave;        // group 0..16383
    const int i = g & 7;
    const int c = lane * 4;

    const us4 pu = *(const us4*)&PQb[(size_t)g * PQS + c];
    us4 qu[7];
#pragma unroll
    for (int jj = 0; jj < 7; ++jj) {
        const int j = jj + (jj >= i ? 1 : 0);
        const int qr = (g & ~7) + j;
        qu[jj] = *(const us4*)&PQb[(size_t)qr * PQS + 256 + c];
    }
    float pe[4], cb[4], cg[4], cbt[4]; bool vl[4];
#pragma unroll
    for (int t = 0; t < 4; ++t) {
        vl[t]  = (c + t) < H;
        pe[t]  = bf2f(pu[t]);
        cb[t]  = vl[t] ? core_b[c + t]  : 0.f;
        cg[t]  = vl[t] ? core_g[c + t]  : 0.f;
        cbt[t] = vl[t] ? core_bt[c + t] : 0.f;
    }
    float z[7][4], red[7][2];
#pragma unroll
    for (int jj = 0; jj < 7; ++jj) {
        float sm = 0.f, sq = 0.f;
#pragma unroll
        for (int t = 0; t < 4; ++t) {
            const float zz = vl[t] ? fmaxf(pe[t] + bf2f(qu[jj][t]) + cb[t], 0.f) : 0.f;
            z[jj][t] = zz; sm += zz; sq = fmaf(zz, zz, sq);
        }
        red[jj][0] = sm; red[jj][1] = sq;
    }
#pragma unroll
    for (int jj = 0; jj < 7; ++jj) {
        red[jj][0] = wave_sum_dpp(red[jj][0]);
        red[jj][1] = wave_sum_dpp(red[jj][1]);
    }
#pragma unroll
    for (int jj = 0; jj < 7; ++jj) {
        const float mu = red[jj][0] * (1.f / H);
        const float rs = __builtin_amdgcn_rsqf(red[jj][1] * (1.f / H) - mu * mu + EPS);
        us4 o;
#pragma unroll
        for (int t = 0; t < 4; ++t)
            o[t] = vl[t] ? f2bf((z[jj][t] - mu) * rs * cg[t] + cbt[t]) : (ushort_t)0;
        *(us4*)&Co[((size_t)g * 7 + jj) * 256 + c] = o;
    }
}

// ================= k_cs: single-buffer GEMM + register-only stats epilogue ==
// GEMM = r8 k_cs verbatim (LDS 28.6 KB, 4 blocks/CU). r10 proved occupancy
// beats intra-block pipelining here — DO NOT add LDS.
// Epilogue wnn-SPECIALIZED (wave-uniform): wnn 0,1 have no att cols (skip
// sma/sqa/szgw chains — provably zero); wnn 3 has no ctx cols (skip smc/sqc
// chains + the whole Cs write). ~35% epilogue-VALU cut, identical outputs.
__global__ __launch_bounds__(512, 4) void k_cs(
    const ushort_t* __restrict__ Co,
    const ushort_t* __restrict__ Wca,   // [384][256] bf16
    const float* __restrict__ ctx_b,
    const float* __restrict__ att_b1, const float* __restrict__ att_g,
    const float* __restrict__ attW2,
    ushort_t* __restrict__ Cs, float* __restrict__ Srow)
{
    __shared__ __align__(16) ushort_t As[64 * 32];    // 4096 B
    __shared__ __align__(16) ushort_t Bs[384 * 32];   // 24576 B
    const int tid = threadIdx.x, lane = tid & 63, wave = tid >> 6;
    const int wmm = wave >> 2, wnn = wave & 3;
    const int R0 = (int)blockIdx.x * 64;

    const int ar = tid >> 2, acb = tid & 3;
    const bool aon = tid < 256;
    const int acl = acb ^ ((ar >> 1) & 3);
    const ushort_t* gA = Co + (size_t)(R0 + ar) * 256 + acl * 8;

    const int q = lane >> 4, fr = lane & 15;

    f32x4 acc[2][6] = {};
    for (int ks = 0; ks < 8; ++ks) {
        const int k0 = ks * 32;
        if (aon) async_copy16(gA + k0, &As[tid * 8]);
#pragma unroll
        for (int it = 0; it < 3; ++it) {
            const int ci  = it * 512 + tid;
            const int rb  = ci >> 2, cb2 = ci & 3;
            const int clb = cb2 ^ ((rb >> 1) & 3);
            async_copy16(Wca + (size_t)rb * 256 + k0 + clb * 8, &Bs[ci * 8]);
        }
        __syncthreads();
        short8 a[2];
#pragma unroll
        for (int ms = 0; ms < 2; ++ms) {
            const int row = wmm * 32 + ms * 16 + fr;
            a[ms] = *(const short8*)&As[(row * 4 + (q ^ ((row >> 1) & 3))) * 8];
        }
#pragma unroll
        for (int nt = 0; nt < 6; ++nt) {
            const int n = wnn * 96 + nt * 16 + fr;
            const short8 b = *(const short8*)&Bs[(n * 4 + (q ^ ((n >> 1) & 3))) * 8];
#pragma unroll
            for (int ms = 0; ms < 2; ++ms)
                acc[ms][nt] = __builtin_amdgcn_mfma_f32_16x16x32_bf16(
                    a[ms], b, acc[ms][nt], 0, 0, 0);
        }
        __syncthreads();
    }

    // ---- epilogue: per-col consts (loaded now; keeps GEMM regs unchanged) ----
    bool eC[6], eA[6]; float b_[6], gw[6];
#pragma unroll
    for (int nt = 0; nt < 6; ++nt) {
        const int col = wnn * 96 + nt * 16 + fr;
        eC[nt] = col < H;
        eA[nt] = (col >= H) && (col < H + HA);
        if (eC[nt])      { b_[nt] = ctx_b[col];      gw[nt] = 0.f; }
        else if (eA[nt]) { const int ca = col - H;
                           b_[nt] = att_b1[ca];
                           gw[nt] = att_g[ca] * attW2[ca]; }
        else             { b_[nt] = gw[nt] = 0.f; }
    }

    // per-ms pass bounds live registers (r8-proven transform)
#pragma unroll
    for (int ms = 0; ms < 2; ++ms) {
        float smc[4] = {}, sqc[4] = {}, sma[4] = {}, sqa[4] = {}, szgw[4] = {};
#pragma unroll
        for (int nt = 0; nt < 6; ++nt) {
#pragma unroll
            for (int reg = 0; reg < 4; ++reg) {
                const float val = acc[ms][nt][reg] + b_[nt];
                if (eC[nt]) {
                    const float zz = fmaxf(val, 0.f);
                    acc[ms][nt][reg] = zz;
                    smc[reg] += zz; sqc[reg] = fmaf(zz, zz, sqc[reg]);
                } else if (eA[nt]) {
                    const float za = ftanh(val);
                    sma[reg] += za; sqa[reg] = fmaf(za, za, sqa[reg]);
                    szgw[reg] = fmaf(za, gw[nt], szgw[reg]);
                }
            }
        }
        // wnn-specialized chains: wnn 0,1 -> ctx only; wnn 3 -> att only.
        // Skipped chains have identically-zero inputs (no matching cols).
        if (wnn <= 2) {
#pragma unroll
            for (int reg = 0; reg < 4; ++reg) {
                smc[reg] = bfly16_sum(smc[reg]);
                sqc[reg] = bfly16_sum(sqc[reg]);
            }
        }
        if (wnn >= 2) {
#pragma unroll
            for (int reg = 0; reg < 4; ++reg) {
                sma[reg]  = bfly16_sum(sma[reg]);
                sqa[reg]  = bfly16_sum(sqa[reg]);
                szgw[reg] = bfly16_sum(szgw[reg]);
            }
        }
        if (fr == 0) {
#pragma unroll
            for (int reg = 0; reg < 4; ++reg) {
                const int row = R0 + wmm * 32 + ms * 16 + q * 4 + reg;
                *(f32x4*)&Srow[(size_t)row * 32 + wnn * 8] =
                    (f32x4){smc[reg], sqc[reg], sma[reg], sqa[reg]};
                Srow[(size_t)row * 32 + wnn * 8 + 4] = szgw[reg];
            }
        }
        // write z (relu'd ctx) to Cs cols [0,256); wnn 3 has no cols < 256
        if (wnn <= 2) {
#pragma unroll
            for (int nt = 0; nt < 6; ++nt) {
                const int col = wnn * 96 + nt * 16 + fr;
                if (col >= 256) continue;
#pragma unroll
                for (int reg = 0; reg < 4; ++reg) {
                    const int row = R0 + wmm * 32 + ms * 16 + q * 4 + reg;
                    Cs[(size_t)row * 256 + col] =
                        eC[nt] ? f2bf(acc[ms][nt][reg]) : (ushort_t)0;
                }
            }
        }
    }
}

// ================= k_eff2: fold partials + gate + weighted sum =================
// One wave per group. Pure streaming: reads 7x256 z (bf16) + 7x20 scalars.
__global__ __launch_bounds__(256) void k_eff2(
    const ushort_t* __restrict__ Cs, const float* __restrict__ Srow,
    const float* __restrict__ ctx_g, const float* __restrict__ ctx_bt,
    const float* __restrict__ att_g, const float* __restrict__ att_bt,
    const float* __restrict__ attW2, const float* __restrict__ att_b2,
    ushort_t* __restrict__ Abuf)
{
    const int wave = threadIdx.x >> 6, lane = threadIdx.x & 63;
    const int g = blockIdx.x * 4 + wave;
    const int c0 = 4 * lane;

    // row-invariant attention sums
    float psg = 0.f, psb = 0.f;
    for (int c = lane; c < HA; c += 64) {
        const float w2 = attW2[c];
        psg = fmaf(att_g[c], w2, psg);
        psb = fmaf(att_bt[c], w2, psb);
    }
    psg = wave_sum_dpp(psg); psb = wave_sum_dpp(psb);
    const float sgw = psg;
    const float ab2 = att_b2[0] + psb;

    float g4[4], bt4[4];
#pragma unroll
    for (int t = 0; t < 4; ++t) {
        const bool vl = (c0 + t) < H;
        g4[t]  = vl ? ctx_g[c0 + t]  : 0.f;
        bt4[t] = vl ? ctx_bt[c0 + t] : 0.f;
    }

    // prefetch z rows
    us4 zv[7];
#pragma unroll
    for (int jj = 0; jj < 7; ++jj)
        zv[jj] = *(const us4*)&Cs[((size_t)g * 7 + jj) * 256 + c0];

    float A4[4] = {0.f, 0.f, 0.f, 0.f};
    float S0 = 0.f, S1 = 0.f;
#pragma unroll
    for (int jj = 0; jj < 7; ++jj) {
        const float* sr = Srow + ((size_t)g * 7 + jj) * 32;
        float s0 = 0.f, s1 = 0.f, s2 = 0.f, s3 = 0.f, s4 = 0.f;
#pragma unroll
        for (int w = 0; w < 4; ++w) {
            const f32x4 v = *(const f32x4*)&sr[w * 8];
            s0 += v[0]; s1 += v[1]; s2 += v[2]; s3 += v[3];
            s4 += sr[w * 8 + 4];
        }
        const float muC = s0 * (1.f / H);
        const float rsC = __builtin_amdgcn_rsqf(s1 * (1.f / H) - muC * muC + EPS);
        const float muA = s2 * (1.f / HA);
        const float rsA = __builtin_amdgcn_rsqf(s3 * (1.f / HA) - muA * muA + EPS);
        const float dot = rsA * (s4 - muA * sgw) + ab2;
        const float ag  = fsigmoid(dot);
        const float cj  = ag * rsC;
        S0 += ag; S1 = fmaf(cj, muC, S1);
#pragma unroll
        for (int e = 0; e < 4; ++e)
            A4[e] = fmaf(cj, bf2f(zv[jj][e]), A4[e]);
    }
    ushort_t o[4];
#pragma unroll
    for (int e = 0; e < 4; ++e)
        o[e] = f2bf(g4[e] * (A4[e] - S1) + bt4[e] * S0);
    ushort_t* dst = Abuf + (size_t)g * KP + H + c0;
    if (c0 + 1 < H) *(us2*)dst       = (us2){o[0], o[1]};
    if (c0 + 3 < H) *(us2*)(dst + 2) = (us2){o[2], o[3]};
}

extern "C" void kernel_launch(void* const* d_in, const int* in_sizes, int n_in,
                              void* d_out, int out_size, void* d_ws, size_t ws_size,
                              hipStream_t stream)
{
    const float* x      = (const float*)d_in[0];
    const float* state  = (const float*)d_in[1];
    const float* enc_W  = (const float*)d_in[2];
    const float* enc_b  = (const float*)d_in[3];
    const float* enc_g  = (const float*)d_in[4];
    const float* enc_bt = (const float*)d_in[5];
    const float* core_W = (const float*)d_in[6];
    const float* core_b = (const float*)d_in[7];
    const float* core_g = (const float*)d_in[8];
    const float* core_bt= (const float*)d_in[9];
    const float* ctx_W  = (const float*)d_in[10];
    const float* ctx_b  = (const float*)d_in[11];
    const float* ctx_g  = (const float*)d_in[12];
    const float* ctx_bt = (const float*)d_in[13];
    const float* att_W1 = (const float*)d_in[14];
    const float* att_b1 = (const float*)d_in[15];
    const float* att_g  = (const float*)d_in[16];
    const float* att_bt = (const float*)d_in[17];
    const float* att_W2 = (const float*)d_in[18];
    const float* att_b2 = (const float*)d_in[19];
    const float* out_W  = (const float*)d_in[20];
    const float* out_b  = (const float*)d_in[21];
    float* out = (float*)d_out;

    // layout (ushort units); Sb/Epre/PQb alias the Cs region (dead before k_cs)
    ushort_t* Abuf = (ushort_t*)d_ws;                   // 16384*1088      (35.7 MB)
    ushort_t* Wt   = Abuf + (size_t)ROWS * KP;          // 256*1088
    ushort_t* Wpq  = Wt + (size_t)256 * KP;             // 512*256
    ushort_t* Wca  = Wpq + (size_t)512 * 256;           // 384*256
    ushort_t* Wenc = Wca + (size_t)384 * 256;           // 256*256
    ushort_t* Co   = Wenc + (size_t)256 * 256;          // 114688*256     (58.7 MB)
    ushort_t* Cs   = Co + (size_t)PROWS * 256;          // 114688*256     (58.7 MB)
    float*    Srow = (float*)(Cs + (size_t)PROWS * 256);// 114688*32 f32  (14.7 MB)
    ushort_t* Sb   = Cs;                                // 16384*256  (aliased)
    ushort_t* Epre = Sb + (size_t)ROWS * 256;           // (unused now)
    ushort_t* PQb  = Epre + (size_t)ROWS * 256;         // 16384*512  (aliased)

    k_prep  <<<3456, 256, 0, stream>>>(out_W, core_W, ctx_W, att_W1, enc_W,
                                       state, x, Wt, Wpq, Wca, Wenc, Sb, Abuf);
    // s1 = LN(relu(state @ enc_W + eb)) -> Abuf cols [0,250)  (fused GEMM+LN)
    k_encln <<<ROWS / 32, 512, 0, stream>>>(Sb, Wenc, enc_b, enc_g, enc_bt, Abuf);
    // PQb = s1 @ [W_top | W_bot]  (bf16 MFMA, N=512 resident, M=32, bf16 out)
    k_gemm_nres<8><<<ROWS / 32, 512, 0, stream>>>(Abuf, KP, Wpq, 256, PQb, PQS,
                                                  nullptr, 8, 512, 1);
    k_core  <<<ROWS / 4, 256, 0, stream>>>(PQb, core_b, core_g, core_bt, Co);
    // single-buffer GEMM + wnn-specialized stats epilogue
    k_cs    <<<PROWS / 64, 512, 0, stream>>>(Co, Wca, ctx_b, att_b1, att_g,
                                             att_W2, Cs, Srow);
    // fold partials + gate + weighted sum -> eff
    k_eff2  <<<ROWS / 4, 256, 0, stream>>>(Cs, Srow, ctx_g, ctx_bt,
                                           att_g, att_bt, att_W2, att_b2, Abuf);
    // out = [s1 | eff | x] @ out_W + b  (bf16 MFMA, N=256, M=32, ping-pong)
    k_gemm_nres<4><<<ROWS / 32, 512, 0, stream>>>(Abuf, KP, Wt, KP, out, H,
                                                  out_b, KP / 32, 250, 0);
}